// Round 1
// 1131.160 us; speedup vs baseline: 1.4419x; 1.4419x over previous
//
#include <hip/hip_runtime.h>

typedef __bf16 bf16;
typedef __bf16 bf16x8 __attribute__((ext_vector_type(8)));
typedef short short8 __attribute__((ext_vector_type(8)));
typedef float f32x4 __attribute__((ext_vector_type(4)));

// Runtime-dual input loader: bf=1 -> buffer holds bf16, else f32.
__device__ __forceinline__ float ldf(const void* p, size_t i, int bf) {
  if (bf) {
    unsigned int u = ((const unsigned short*)p)[i];
    union { unsigned int ui; float f; } c;
    c.ui = u << 16;
    return c.f;
  }
  return ((const float*)p)[i];
}

// XOR swizzle for bf16 LDS tiles read as ds_read_b128 (16B chunks).
// Spreads 16-consecutive-row reads over 8 slots, <=2-way conflict; also keeps
// the 4 rows {r, r+4, r+8, r+12} touched by a D-frag write on distinct slots.
__device__ __forceinline__ int sw8(int r) { return ((r ^ (r >> 2)) & 7) << 3; }

// ---------------------------------------------------------------------------
// Dtype detector (unchanged).
// ---------------------------------------------------------------------------
__global__ void k_detect(const void* x, int* flag)
{
  int tid = threadIdx.x;  // 64 threads
  int cnt = 0;
  for (int j = 0; j < 4; j++) {
    int i = (tid * 4 + j) * 2;
    unsigned int u = ((const unsigned short*)x)[i];
    union { unsigned int ui; float f; } c;
    c.ui = u << 16;
    float a = fabsf(c.f);
    if (a >= 1e-4f && a <= 100.f) cnt++;
  }
  for (int m = 1; m < 64; m <<= 1) cnt += __shfl_xor(cnt, m);
  if (tid == 0) *flag = (cnt > 128) ? 1 : 0;
}

// ---------------------------------------------------------------------------
// ck/cv = context @ Wck/Wcv + bias   (4096 rows x 64) -> f32 internal
// ---------------------------------------------------------------------------
__global__ __launch_bounds__(256)
void k_ctx(const int* flagp, const void* ctx, const void* Wck, const void* bck,
           const void* Wcv, const void* bcv, float* __restrict__ ck,
           float* __restrict__ cv)
{
  const int bf = *flagp;
  int rid = blockIdx.x * 4 + (threadIdx.x >> 6);
  int dp = threadIdx.x & 63;
  float a1 = 0.f, a2 = 0.f;
  for (int e = 0; e < 64; e++) {
    float c = ldf(ctx, (size_t)rid * 64 + e, bf);
    a1 += c * ldf(Wck, e * 64 + dp, bf);
    a2 += c * ldf(Wcv, e * 64 + dp, bf);
  }
  ck[rid * 64 + dp] = a1 + ldf(bck, dp, bf);
  cv[rid * 64 + dp] = a2 + ldf(bcv, dp, bf);
}

// ---------------------------------------------------------------------------
// ckq[s][din] = Wcq-row(din) . ck[s] ; cqb[s] = bcq . ck[s]
// Gk[h*64+j][din] = Wk-row(din) . G[h][j] ; gb[h*64+j] = G[h][j] . bk
// ---------------------------------------------------------------------------
__global__ __launch_bounds__(256)
void k_fold(const int* flagp, const float* __restrict__ ck, const void* Wcq,
            const void* bcq, const void* qg, const void* Wk, const void* bk,
            float* __restrict__ ckq, float* __restrict__ cqb,
            float* __restrict__ Gk, float* __restrict__ gb)
{
  const int bf = *flagp;
  int bid = blockIdx.x, tid = threadIdx.x;
  if (bid < 1024) {
    int rid = bid * 4 + (tid >> 6), dp = tid & 63;
    const float* c = ck + (size_t)rid * 64;
    float a = 0.f;
    for (int o = 0; o < 64; o++) a += c[o] * ldf(Wcq, dp * 64 + o, bf);
    ckq[rid * 64 + dp] = a;
    if (dp == 0) {
      float s = 0.f;
      for (int o = 0; o < 64; o++) s += ldf(bcq, o, bf) * c[o];
      cqb[rid] = s;
    }
  } else {
    int i = (bid - 1024) * 256 + tid;    // [0, 32768)
    int row = i >> 6, dIn = i & 63;
    float s = 0.f;
    for (int d = 0; d < 64; d++)
      s += ldf(qg, (size_t)row * 64 + d, bf) * ldf(Wk, dIn * 64 + d, bf);
    Gk[i] = s;
    if (dIn == 0) {
      float t = 0.f;
      for (int d = 0; d < 64; d++)
        t += ldf(qg, (size_t)row * 64 + d, bf) * ldf(bk, d, bf);
      gb[row] = t;
    }
  }
}

// ---------------------------------------------------------------------------
// Tiled GEMM: out(Mx512) = A(Mx512) @ W(512x512) + bias. (unchanged)
// ---------------------------------------------------------------------------
__global__ __launch_bounds__(256)
void k_gemm(const int* flagp, const void* A, const int amode, const void* W,
            const void* bias, void* out, const int omode)
{
  const int bf = *flagp;
  __shared__ float As[16][68];
  __shared__ float Ws[16][68];
  const int tid = threadIdx.x;
  const int tx = tid & 15, ty = tid >> 4;
  const int n0 = blockIdx.x * 64, m0 = blockIdx.y * 64;
  float acc[4][4] = {};

  for (int k0 = 0; k0 < 512; k0 += 16) {
    __syncthreads();
    for (int e = tid; e < 1024; e += 256) {
      int kk = e & 15, mm = e >> 4;
      size_t ai = (size_t)(m0 + mm) * 512 + k0 + kk;
      As[kk][mm] = (amode == 1) ? (float)((const bf16*)A)[ai] : ldf(A, ai, bf);
      int kk2 = e >> 6, nn = e & 63;
      Ws[kk2][nn] = ldf(W, (size_t)(k0 + kk2) * 512 + n0 + nn, bf);
    }
    __syncthreads();
#pragma unroll
    for (int kk = 0; kk < 16; kk++) {
      float a[4], b[4];
#pragma unroll
      for (int i = 0; i < 4; i++) a[i] = As[kk][ty * 4 + i];
#pragma unroll
      for (int j = 0; j < 4; j++) b[j] = Ws[kk][tx * 4 + j];
#pragma unroll
      for (int i = 0; i < 4; i++)
#pragma unroll
        for (int j = 0; j < 4; j++) acc[i][j] += a[i] * b[j];
    }
  }
#pragma unroll
  for (int j = 0; j < 4; j++) {
    float bj = ldf(bias, n0 + tx * 4 + j, bf);
#pragma unroll
    for (int i = 0; i < 4; i++) {
      float v = acc[i][j] + bj;
      size_t oi = (size_t)(m0 + ty * 4 + i) * 512 + n0 + tx * 4 + j;
      if (omode == 0 || bf) ((bf16*)out)[oi] = (bf16)v;
      else                  ((float*)out)[oi] = v;
    }
  }
}

// ---------------------------------------------------------------------------
// Stage A (z pre-Wv): unchanged.
// ---------------------------------------------------------------------------
__global__ __launch_bounds__(256)
void k_stageA(const float* __restrict__ Gk, const float* __restrict__ gb,
              const bf16* __restrict__ xm, float* __restrict__ zpre,
              float* __restrict__ lbuf)
{
  __shared__ float Gkj[64];
  __shared__ float red[4][65];
  const int tid = threadIdx.x, lane = tid & 63, w = tid >> 6;
  const int bh = blockIdx.x, j = blockIdx.y;
  const int b = bh >> 3, h = bh & 7;
  if (tid < 64) Gkj[tid] = Gk[(size_t)(h * 64 + j) * 64 + tid];
  __syncthreads();
  const float gbv = gb[h * 64 + j];

  float zp[64];
#pragma unroll
  for (int d = 0; d < 64; d++) zp[d] = 0.f;
  float lp = 0.f;

  for (int n = tid; n < 16384; n += 256) {
    const bf16* xr = xm + ((size_t)(b * 16384 + n) * 512 + h * 64);
    float xs[64];
#pragma unroll
    for (int c = 0; c < 8; c++) {
      bf16x8 vv = *(const bf16x8*)(xr + c * 8);
#pragma unroll
      for (int jj = 0; jj < 8; jj++) xs[c * 8 + jj] = (float)vv[jj];
    }
    float s = 0.f;
#pragma unroll
    for (int d = 0; d < 64; d++) s += Gkj[d] * xs[d];
    float e = __expf(s + gbv);
    lp += e;
#pragma unroll
    for (int d = 0; d < 64; d++) zp[d] += e * xs[d];
  }

#pragma unroll
  for (int d = 0; d < 64; d++) {
    float v = zp[d];
    for (int m = 1; m < 64; m <<= 1) v += __shfl_xor(v, m);
    zp[d] = v;
  }
  for (int m = 1; m < 64; m <<= 1) lp += __shfl_xor(lp, m);

  if (lane == 0) {
#pragma unroll
    for (int d = 0; d < 64; d++) red[w][d] = zp[d];
    red[w][64] = lp;
  }
  __syncthreads();
  if (tid < 64)
    zpre[((size_t)bh * 64 + j) * 64 + tid] =
        red[0][tid] + red[1][tid] + red[2][tid] + red[3][tid];
  if (tid == 64)
    lbuf[bh * 64 + j] = red[0][64] + red[1][64] + red[2][64] + red[3][64];
}

// z[bh][j][d] = (zpre[j,:]/l_j) @ Wv[:,d] + bv[d]   (unchanged)
__global__ __launch_bounds__(256)
void k_znorm(const int* flagp, const float* __restrict__ zpre,
             const float* __restrict__ lbuf, const void* Wv, const void* bv,
             float* __restrict__ z)
{
  const int bf = *flagp;
  int bh = blockIdx.x;
  for (int i = threadIdx.x; i < 4096; i += 256) {
    int j = i >> 6, d = i & 63;
    float inv = 1.f / lbuf[bh * 64 + j];
    float s = 0.f;
    for (int e = 0; e < 64; e++)
      s += zpre[(size_t)bh * 4096 + j * 64 + e] * ldf(Wv, e * 64 + d, bf);
    z[(size_t)bh * 4096 + i] = s * inv + ldf(bv, d, bf);
  }
}

// ---------------------------------------------------------------------------
// Merged MFMA flash attention (self over 64 globals + cross over 256 ctx).
// One (b,h) per blockIdx.y, 256 token rows per block, 8 waves x 32 rows.
// attn_part<NCH>: chunked S-loop (32 ctx per chunk):
//   QK MFMA (A = X frags, B = row-major [n][64] bf16 LDS, swizzled)
//   exp(+bias) on D-frags, per-wave LDS transpose to A-layout bf16 P
//   PV MFMA (B = V^T [d][NCTX] bf16 LDS, swizzled), f32 accumulate.
// ---------------------------------------------------------------------------
template <int NCH, int VSTR>
__device__ __forceinline__ void attn_part(
    const bf16* __restrict__ Bq, const bf16* __restrict__ BvT,
    const float* __restrict__ biasL, const short8 (&ax)[2][2],
    bf16* __restrict__ Pw, int lo, int hi,
    f32x4 (&accO)[2][4], float (&lsum)[2][4])
{
#pragma unroll
  for (int ch = 0; ch < NCH; ch++) {
    const int c0 = ch * 32;
    f32x4 s[2][2];
#pragma unroll
    for (int rt = 0; rt < 2; rt++)
#pragma unroll
      for (int ct = 0; ct < 2; ct++) s[rt][ct] = f32x4{0.f, 0.f, 0.f, 0.f};
#pragma unroll
    for (int ks = 0; ks < 2; ks++) {
      short8 bq[2];
#pragma unroll
      for (int ct = 0; ct < 2; ct++) {
        int n = c0 + ct * 16 + lo;
        bq[ct] = *(const short8*)(Bq + n * 64 + ((ks * 32 + hi * 8) ^ sw8(n)));
      }
#pragma unroll
      for (int rt = 0; rt < 2; rt++)
#pragma unroll
        for (int ct = 0; ct < 2; ct++)
          s[rt][ct] = __builtin_amdgcn_mfma_f32_16x16x32_bf16(
              ax[rt][ks], bq[ct], s[rt][ct], 0, 0, 0);
    }
    // exp + bias, stage P into per-wave LDS (D-layout -> A-layout transpose)
    float b0 = biasL[c0 + lo], b1 = biasL[c0 + 16 + lo];
#pragma unroll
    for (int rt = 0; rt < 2; rt++)
#pragma unroll
      for (int r = 0; r < 4; r++) {
        int prow = rt * 16 + hi * 4 + r;
        float e0 = __expf(s[rt][0][r] + b0);
        float e1 = __expf(s[rt][1][r] + b1);
        lsum[rt][r] += e0 + e1;
        Pw[prow * 64 + (lo ^ sw8(prow))] = (bf16)e0;
        Pw[prow * 64 + ((16 + lo) ^ sw8(prow))] = (bf16)e1;
      }
    // PV
    short8 ap[2];
#pragma unroll
    for (int rt = 0; rt < 2; rt++) {
      int prow = rt * 16 + lo;
      ap[rt] = *(const short8*)(Pw + prow * 64 + ((hi * 8) ^ sw8(prow)));
    }
#pragma unroll
    for (int dt = 0; dt < 4; dt++) {
      int d = dt * 16 + lo;
      short8 bv = *(const short8*)(BvT + d * VSTR + ((c0 + hi * 8) ^ sw8(d)));
#pragma unroll
      for (int rt = 0; rt < 2; rt++)
        accO[rt][dt] = __builtin_amdgcn_mfma_f32_16x16x32_bf16(
            ap[rt], bv, accO[rt][dt], 0, 0, 0);
    }
  }
}

__global__ __launch_bounds__(512)
void k_attn(const int* flagp, const float* __restrict__ Gk,
            const float* __restrict__ gb, const float* __restrict__ z,
            const float* __restrict__ ckq, const float* __restrict__ cqb,
            const float* __restrict__ cv, const bf16* __restrict__ xm,
            const void* smix, bf16* __restrict__ selfmid)
{
  __shared__ __attribute__((aligned(16))) bf16 GkB[64 * 64];    //  8 KiB
  __shared__ __attribute__((aligned(16))) bf16 zTB[64 * 64];    //  8 KiB
  __shared__ __attribute__((aligned(16))) bf16 ckqB[256 * 64];  // 32 KiB
  __shared__ __attribute__((aligned(16))) bf16 cvTB[64 * 256];  // 32 KiB
  __shared__ __attribute__((aligned(16))) bf16 Pst[8][32 * 64]; // 32 KiB
  __shared__ float cqbL[256];
  __shared__ float gbL[64];

  const int tid = threadIdx.x;
  const int bh = blockIdx.y, b = bh >> 3, h = bh & 7;

  // ---- stage (bf16 convert + swizzle; V matrices transposed to [d][s]) ----
  {
    int r = tid >> 3, c0 = (tid & 7) * 8;
    const float* g = Gk + ((size_t)(h * 64 + r)) * 64 + c0;
    bf16x8 v;
#pragma unroll
    for (int t = 0; t < 8; t++) v[t] = (bf16)g[t];
    *(bf16x8*)&GkB[r * 64 + (c0 ^ sw8(r))] = v;
    const float* zp = z + (size_t)bh * 4096 + (size_t)c0 * 64 + r;
#pragma unroll
    for (int t = 0; t < 8; t++) v[t] = (bf16)zp[t * 64];
    *(bf16x8*)&zTB[r * 64 + (c0 ^ sw8(r))] = v;
  }
#pragma unroll
  for (int rr = 0; rr < 4; rr++) {
    int idx = tid + rr * 512;
    int r = idx >> 3, c0 = (idx & 7) * 8;
    const float* c = ckq + (size_t)bh * 16384 + (size_t)r * 64 + c0;
    bf16x8 v;
#pragma unroll
    for (int t = 0; t < 8; t++) v[t] = (bf16)c[t];
    *(bf16x8*)&ckqB[r * 64 + (c0 ^ sw8(r))] = v;
  }
  {
    int d = tid >> 3, s0 = (tid & 7) * 32;
#pragma unroll
    for (int cc = 0; cc < 4; cc++) {
      int sb = s0 + cc * 8;
      bf16x8 v;
#pragma unroll
      for (int t = 0; t < 8; t++)
        v[t] = (bf16)cv[(size_t)bh * 16384 + (size_t)(sb + t) * 64 + d];
      *(bf16x8*)&cvTB[d * 256 + (sb ^ sw8(d))] = v;
    }
  }
  if (tid < 256)      cqbL[tid] = cqb[bh * 256 + tid];
  else if (tid < 320) gbL[tid - 256] = gb[h * 64 + (tid - 256)];
  __syncthreads();

  const int wid = tid >> 6, lane = tid & 63;
  const int lo = lane & 15, hi = lane >> 4;
  const int m0 = blockIdx.x * 256 + wid * 32;
  bf16* Pw = Pst[wid];

  // X A-frags (shared by self-QK and cross-QK): row = lane&15, k contiguous 8
  short8 ax[2][2];
#pragma unroll
  for (int rt = 0; rt < 2; rt++)
#pragma unroll
    for (int ks = 0; ks < 2; ks++)
      ax[rt][ks] = *(const short8*)(xm +
          (size_t)(b * 16384 + m0 + rt * 16 + lo) * 512 + h * 64 +
          ks * 32 + hi * 8);

  f32x4 accS[2][4], accC[2][4];
  float l1[2][4], l2[2][4];
#pragma unroll
  for (int rt = 0; rt < 2; rt++)
#pragma unroll
    for (int dt = 0; dt < 4; dt++) {
      accS[rt][dt] = f32x4{0.f, 0.f, 0.f, 0.f};
      accC[rt][dt] = f32x4{0.f, 0.f, 0.f, 0.f};
      l1[rt][dt] = 0.f;
      l2[rt][dt] = 0.f;
    }

  attn_part<2, 64>(GkB, zTB, gbL, ax, Pw, lo, hi, accS, l1);     // self (64 j)
  attn_part<8, 256>(ckqB, cvTB, cqbL, ax, Pw, lo, hi, accC, l2); // cross (256 s)

  // row-sum reduce across the 16 lanes holding the row's columns
#pragma unroll
  for (int rt = 0; rt < 2; rt++)
#pragma unroll
    for (int r = 0; r < 4; r++) {
      float a = l1[rt][r], c = l2[rt][r];
      for (int m = 1; m < 16; m <<= 1) {
        a += __shfl_xor(a, m);
        c += __shfl_xor(c, m);
      }
      l1[rt][r] = 1.f / a;
      l2[rt][r] = 1.f / c;
    }

  const int bf = *flagp;
  const float wmix = 1.f / (1.f + __expf(-ldf(smix, 0, bf)));
#pragma unroll
  for (int rt = 0; rt < 2; rt++)
#pragma unroll
    for (int r = 0; r < 4; r++) {
      int row = m0 + rt * 16 + hi * 4 + r;
      size_t off = (size_t)(b * 16384 + row) * 512 + h * 64;
#pragma unroll
      for (int dt = 0; dt < 4; dt++) {
        float vS = accS[rt][dt][r] * l1[rt][r];
        float vC = accC[rt][dt][r] * l2[rt][r];
        selfmid[off + dt * 16 + lo] = (bf16)(wmix * vS + (1.f - wmix) * vC);
      }
    }
}

// ---------------------------------------------------------------------------
extern "C" void kernel_launch(void* const* d_in, const int* in_sizes, int n_in,
                              void* d_out, int out_size, void* d_ws, size_t ws_size,
                              hipStream_t stream)
{
  const void* x    = d_in[0];
  const void* ctx  = d_in[1];
  const void* qg   = d_in[2];
  const void* Wp   = d_in[3];  const void* bp  = d_in[4];
  const void* Wk   = d_in[5];  const void* bk  = d_in[6];
  const void* Wv   = d_in[7];  const void* bv  = d_in[8];
  const void* Wcq  = d_in[9];  const void* bcq = d_in[10];
  const void* Wck  = d_in[11]; const void* bck = d_in[12];
  const void* Wcv  = d_in[13]; const void* bcv = d_in[14];
  const void* smix = d_in[15];
  const void* Wo   = d_in[16]; const void* bo  = d_in[17];

  char* ws = (char*)d_ws;
  int*   flag    = (int*)(ws);                   // 256 B reserved
  float* ck      = (float*)(ws + 256);           // 1,048,576
  float* cv      = (float*)(ws + 1048832);       // 1,048,576
  float* ckq     = (float*)(ws + 2097408);       // 1,048,576
  float* cqb     = (float*)(ws + 3145984);       // 16,384
  float* Gk      = (float*)(ws + 3162368);       // 131,072
  float* gb      = (float*)(ws + 3293440);       // 2,048
  float* lbuf    = (float*)(ws + 3295488);       // 4,096
  float* zpre    = (float*)(ws + 3299584);       // 1,048,576
  float* z       = (float*)(ws + 4348160);       // 1,048,576
  bf16*  xm      = (bf16*)(ws + 5396736);        // 33,554,432 (bf16)
  bf16*  selfmid = (bf16*)(ws + 38951168);       // 33,554,432 (bf16) -> ~69 MB

  k_detect<<<1, 64, 0, stream>>>(x, flag);

  k_ctx<<<1024, 256, 0, stream>>>(flag, ctx, Wck, bck, Wcv, bcv, ck, cv);
  k_fold<<<1152, 256, 0, stream>>>(flag, ck, Wcq, bcq, qg, Wk, bk,
                                   ckq, cqb, Gk, gb);

  // x_mid (flat (b,n,h*64+d), bf16) = x @ Wp + bp
  k_gemm<<<dim3(8, 512), 256, 0, stream>>>(flag, x, 0, Wp, bp, xm, 0);

  k_stageA<<<dim3(16, 64), 256, 0, stream>>>(Gk, gb, xm, zpre, lbuf);
  k_znorm<<<16, 256, 0, stream>>>(flag, zpre, lbuf, Wv, bv, z);

  // merged MFMA self+cross attention + sigmoid mix -> selfmid
  k_attn<<<dim3(64, 16), 512, 0, stream>>>(flag, Gk, gb, z, ckq, cqb, cv, xm,
                                           smix, selfmid);

  // out = selfmid @ Wo + bo  (output dtype chosen by flag)
  k_gemm<<<dim3(8, 512), 256, 0, stream>>>(flag, selfmid, 1, Wo, bo, d_out, 1);
}

// Round 2
// 692.056 us; speedup vs baseline: 2.3568x; 1.6345x over previous
//
#include <hip/hip_runtime.h>

typedef __bf16 bf16;
typedef __bf16 bf16x8 __attribute__((ext_vector_type(8)));
typedef short short8 __attribute__((ext_vector_type(8)));
typedef float f32x4 __attribute__((ext_vector_type(4)));

// Runtime-dual input loader: bf=1 -> buffer holds bf16, else f32.
__device__ __forceinline__ float ldf(const void* p, size_t i, int bf) {
  if (bf) {
    unsigned int u = ((const unsigned short*)p)[i];
    union { unsigned int ui; float f; } c;
    c.ui = u << 16;
    return c.f;
  }
  return ((const float*)p)[i];
}

// XOR swizzle for bf16 LDS tiles read as ds_read_b128 (16B chunks).
__device__ __forceinline__ int sw8(int r) { return ((r ^ (r >> 2)) & 7) << 3; }

// ---------------------------------------------------------------------------
// Dtype detector (unchanged).
// ---------------------------------------------------------------------------
__global__ void k_detect(const void* x, int* flag)
{
  int tid = threadIdx.x;  // 64 threads
  int cnt = 0;
  for (int j = 0; j < 4; j++) {
    int i = (tid * 4 + j) * 2;
    unsigned int u = ((const unsigned short*)x)[i];
    union { unsigned int ui; float f; } c;
    c.ui = u << 16;
    float a = fabsf(c.f);
    if (a >= 1e-4f && a <= 100.f) cnt++;
  }
  for (int m = 1; m < 64; m <<= 1) cnt += __shfl_xor(cnt, m);
  if (tid == 0) *flag = (cnt > 128) ? 1 : 0;
}

// ---------------------------------------------------------------------------
// ck/cv = context @ Wck/Wcv + bias   (4096 rows x 64) -> f32 internal
// ---------------------------------------------------------------------------
__global__ __launch_bounds__(256)
void k_ctx(const int* flagp, const void* ctx, const void* Wck, const void* bck,
           const void* Wcv, const void* bcv, float* __restrict__ ck,
           float* __restrict__ cv)
{
  const int bf = *flagp;
  int rid = blockIdx.x * 4 + (threadIdx.x >> 6);
  int dp = threadIdx.x & 63;
  float a1 = 0.f, a2 = 0.f;
  for (int e = 0; e < 64; e++) {
    float c = ldf(ctx, (size_t)rid * 64 + e, bf);
    a1 += c * ldf(Wck, e * 64 + dp, bf);
    a2 += c * ldf(Wcv, e * 64 + dp, bf);
  }
  ck[rid * 64 + dp] = a1 + ldf(bck, dp, bf);
  cv[rid * 64 + dp] = a2 + ldf(bcv, dp, bf);
}

// ---------------------------------------------------------------------------
// ckq[s][din] = Wcq-row(din) . ck[s] ; cqb[s] = bcq . ck[s]
// Gk[h*64+j][din] = Wk-row(din) . G[h][j] ; gb[h*64+j] = G[h][j] . bk
// ---------------------------------------------------------------------------
__global__ __launch_bounds__(256)
void k_fold(const int* flagp, const float* __restrict__ ck, const void* Wcq,
            const void* bcq, const void* qg, const void* Wk, const void* bk,
            float* __restrict__ ckq, float* __restrict__ cqb,
            float* __restrict__ Gk, float* __restrict__ gb)
{
  const int bf = *flagp;
  int bid = blockIdx.x, tid = threadIdx.x;
  if (bid < 1024) {
    int rid = bid * 4 + (tid >> 6), dp = tid & 63;
    const float* c = ck + (size_t)rid * 64;
    float a = 0.f;
    for (int o = 0; o < 64; o++) a += c[o] * ldf(Wcq, dp * 64 + o, bf);
    ckq[rid * 64 + dp] = a;
    if (dp == 0) {
      float s = 0.f;
      for (int o = 0; o < 64; o++) s += ldf(bcq, o, bf) * c[o];
      cqb[rid] = s;
    }
  } else {
    int i = (bid - 1024) * 256 + tid;    // [0, 32768)
    int row = i >> 6, dIn = i & 63;
    float s = 0.f;
    for (int d = 0; d < 64; d++)
      s += ldf(qg, (size_t)row * 64 + d, bf) * ldf(Wk, dIn * 64 + d, bf);
    Gk[i] = s;
    if (dIn == 0) {
      float t = 0.f;
      for (int d = 0; d < 64; d++)
        t += ldf(qg, (size_t)row * 64 + d, bf) * ldf(bk, d, bf);
      gb[row] = t;
    }
  }
}

// ---------------------------------------------------------------------------
// Weight prep: WT[n][k] = (bf16)W[k][n] for Wp (blocks 0..63) and Wo (64..127).
// Runs after k_fold; WpT/WoT live in the dead ck region.
// ---------------------------------------------------------------------------
__global__ __launch_bounds__(256)
void k_wtr(const int* flagp, const void* Wp, const void* Wo,
           bf16* __restrict__ WpT, bf16* __restrict__ WoT)
{
  const int bf = *flagp;
  const int bid = blockIdx.x, tid = threadIdx.x;
  const void* W = (bid < 64) ? Wp : Wo;
  bf16* WT = (bid < 64) ? WpT : WoT;
  const int tb = bid & 63, kb = tb & 7, nb = tb >> 3;
  __shared__ float t[64][65];
  for (int e = tid; e < 4096; e += 256) {
    int k = e >> 6, n = e & 63;
    t[k][n] = ldf(W, (size_t)(kb * 64 + k) * 512 + nb * 64 + n, bf);
  }
  __syncthreads();
  for (int e = tid; e < 4096; e += 256) {
    int n = e >> 6, k = e & 63;
    WT[(size_t)(nb * 64 + n) * 512 + kb * 64 + k] = (bf16)t[k][n];
  }
}

// ---------------------------------------------------------------------------
// MFMA GEMM: out(Mx512) = A(Mx512) @ W(512x512) + bias, W given as WT[n][k] bf16.
// 128x128 tile, BK=64, 4 waves (2x2) x 64x64 each, double-buffered swizzled LDS.
// amode: 0 = A external (flag-dual), 1 = A bf16 internal.
// omode: 0 = out bf16 internal, 1 = out external (flag ? bf16 : f32).
// ---------------------------------------------------------------------------
__device__ __forceinline__ void g_stage(const void* A, int abf, const bf16* WT,
                                        int m0, int n0, int kt,
                                        bf16* __restrict__ As,
                                        bf16* __restrict__ Bs,
                                        int srow, int schk)
{
#pragma unroll
  for (int i = 0; i < 4; i++) {
    const int row = i * 32 + srow;
    const int koff = kt * 64 + schk * 8;
    bf16x8 v;
    if (abf) {
      v = *(const bf16x8*)((const bf16*)A + (size_t)(m0 + row) * 512 + koff);
    } else {
      const float* ap = (const float*)A + (size_t)(m0 + row) * 512 + koff;
      f32x4 f0 = *(const f32x4*)ap;
      f32x4 f1 = *(const f32x4*)(ap + 4);
#pragma unroll
      for (int j = 0; j < 4; j++) { v[j] = (bf16)f0[j]; v[4 + j] = (bf16)f1[j]; }
    }
    *(bf16x8*)&As[row * 64 + ((schk * 8) ^ sw8(row))] = v;
    bf16x8 w = *(const bf16x8*)(WT + (size_t)(n0 + row) * 512 + koff);
    *(bf16x8*)&Bs[row * 64 + ((schk * 8) ^ sw8(row))] = w;
  }
}

__global__ __launch_bounds__(256)
void k_gemm_mfma(const int* flagp, const void* A, const int amode,
                 const bf16* __restrict__ WT, const void* bias, void* out,
                 const int omode)
{
  __shared__ __attribute__((aligned(16))) bf16 AsB[2][128 * 64];  // 16 KiB x2
  __shared__ __attribute__((aligned(16))) bf16 BsB[2][128 * 64];  // 16 KiB x2

  const int bf = *flagp;
  const int abf = (amode == 1) || bf;
  const int tid = threadIdx.x;
  const int srow = tid >> 3, schk = tid & 7;
  const int m0 = blockIdx.y * 128, n0 = blockIdx.x * 128;

  const int lane = tid & 63, wid = tid >> 6;
  const int lo = lane & 15, hi = lane >> 4;
  const int wm = (wid >> 1) * 64, wn = (wid & 1) * 64;

  f32x4 acc[4][4];
#pragma unroll
  for (int mt = 0; mt < 4; mt++)
#pragma unroll
    for (int nt = 0; nt < 4; nt++) acc[mt][nt] = f32x4{0.f, 0.f, 0.f, 0.f};

  g_stage(A, abf, WT, m0, n0, 0, AsB[0], BsB[0], srow, schk);
  __syncthreads();

  int cur = 0;
  for (int kt = 0; kt < 8; kt++) {
    if (kt < 7)
      g_stage(A, abf, WT, m0, n0, kt + 1, AsB[cur ^ 1], BsB[cur ^ 1], srow, schk);
    const bf16* Asc = AsB[cur];
    const bf16* Bsc = BsB[cur];
#pragma unroll
    for (int ks = 0; ks < 2; ks++) {
      short8 af[4], bq[4];
#pragma unroll
      for (int mt = 0; mt < 4; mt++) {
        int r = wm + mt * 16 + lo;
        af[mt] = *(const short8*)&Asc[r * 64 + ((ks * 32 + hi * 8) ^ sw8(r))];
      }
#pragma unroll
      for (int nt = 0; nt < 4; nt++) {
        int r = wn + nt * 16 + lo;
        bq[nt] = *(const short8*)&Bsc[r * 64 + ((ks * 32 + hi * 8) ^ sw8(r))];
      }
#pragma unroll
      for (int mt = 0; mt < 4; mt++)
#pragma unroll
        for (int nt = 0; nt < 4; nt++)
          acc[mt][nt] = __builtin_amdgcn_mfma_f32_16x16x32_bf16(
              af[mt], bq[nt], acc[mt][nt], 0, 0, 0);
    }
    __syncthreads();
    cur ^= 1;
  }

#pragma unroll
  for (int nt = 0; nt < 4; nt++) {
    const int col = n0 + wn + nt * 16 + lo;
    const float bj = ldf(bias, col, bf);
#pragma unroll
    for (int mt = 0; mt < 4; mt++)
#pragma unroll
      for (int r = 0; r < 4; r++) {
        const int rowg = m0 + wm + mt * 16 + hi * 4 + r;
        const float v = acc[mt][nt][r] + bj;
        const size_t oi = (size_t)rowg * 512 + col;
        if (omode == 0 || bf) ((bf16*)out)[oi] = (bf16)v;
        else                  ((float*)out)[oi] = v;
      }
  }
}

// ---------------------------------------------------------------------------
// Stage A (z pre-Wv): unchanged.
// ---------------------------------------------------------------------------
__global__ __launch_bounds__(256)
void k_stageA(const float* __restrict__ Gk, const float* __restrict__ gb,
              const bf16* __restrict__ xm, float* __restrict__ zpre,
              float* __restrict__ lbuf)
{
  __shared__ float Gkj[64];
  __shared__ float red[4][65];
  const int tid = threadIdx.x, lane = tid & 63, w = tid >> 6;
  const int bh = blockIdx.x, j = blockIdx.y;
  const int b = bh >> 3, h = bh & 7;
  if (tid < 64) Gkj[tid] = Gk[(size_t)(h * 64 + j) * 64 + tid];
  __syncthreads();
  const float gbv = gb[h * 64 + j];

  float zp[64];
#pragma unroll
  for (int d = 0; d < 64; d++) zp[d] = 0.f;
  float lp = 0.f;

  for (int n = tid; n < 16384; n += 256) {
    const bf16* xr = xm + ((size_t)(b * 16384 + n) * 512 + h * 64);
    float xs[64];
#pragma unroll
    for (int c = 0; c < 8; c++) {
      bf16x8 vv = *(const bf16x8*)(xr + c * 8);
#pragma unroll
      for (int jj = 0; jj < 8; jj++) xs[c * 8 + jj] = (float)vv[jj];
    }
    float s = 0.f;
#pragma unroll
    for (int d = 0; d < 64; d++) s += Gkj[d] * xs[d];
    float e = __expf(s + gbv);
    lp += e;
#pragma unroll
    for (int d = 0; d < 64; d++) zp[d] += e * xs[d];
  }

#pragma unroll
  for (int d = 0; d < 64; d++) {
    float v = zp[d];
    for (int m = 1; m < 64; m <<= 1) v += __shfl_xor(v, m);
    zp[d] = v;
  }
  for (int m = 1; m < 64; m <<= 1) lp += __shfl_xor(lp, m);

  if (lane == 0) {
#pragma unroll
    for (int d = 0; d < 64; d++) red[w][d] = zp[d];
    red[w][64] = lp;
  }
  __syncthreads();
  if (tid < 64)
    zpre[((size_t)bh * 64 + j) * 64 + tid] =
        red[0][tid] + red[1][tid] + red[2][tid] + red[3][tid];
  if (tid == 64)
    lbuf[bh * 64 + j] = red[0][64] + red[1][64] + red[2][64] + red[3][64];
}

// z[bh][j][d] = (zpre[j,:]/l_j) @ Wv[:,d] + bv[d]   (unchanged)
__global__ __launch_bounds__(256)
void k_znorm(const int* flagp, const float* __restrict__ zpre,
             const float* __restrict__ lbuf, const void* Wv, const void* bv,
             float* __restrict__ z)
{
  const int bf = *flagp;
  int bh = blockIdx.x;
  for (int i = threadIdx.x; i < 4096; i += 256) {
    int j = i >> 6, d = i & 63;
    float inv = 1.f / lbuf[bh * 64 + j];
    float s = 0.f;
    for (int e = 0; e < 64; e++)
      s += zpre[(size_t)bh * 4096 + j * 64 + e] * ldf(Wv, e * 64 + d, bf);
    z[(size_t)bh * 4096 + i] = s * inv + ldf(bv, d, bf);
  }
}

// ---------------------------------------------------------------------------
// Merged MFMA flash attention (self over 64 globals + cross over 256 ctx).
// ---------------------------------------------------------------------------
template <int NCH, int VSTR>
__device__ __forceinline__ void attn_part(
    const bf16* __restrict__ Bq, const bf16* __restrict__ BvT,
    const float* __restrict__ biasL, const short8 (&ax)[2][2],
    bf16* __restrict__ Pw, int lo, int hi,
    f32x4 (&accO)[2][4], float (&lsum)[2][4])
{
#pragma unroll
  for (int ch = 0; ch < NCH; ch++) {
    const int c0 = ch * 32;
    f32x4 s[2][2];
#pragma unroll
    for (int rt = 0; rt < 2; rt++)
#pragma unroll
      for (int ct = 0; ct < 2; ct++) s[rt][ct] = f32x4{0.f, 0.f, 0.f, 0.f};
#pragma unroll
    for (int ks = 0; ks < 2; ks++) {
      short8 bq[2];
#pragma unroll
      for (int ct = 0; ct < 2; ct++) {
        int n = c0 + ct * 16 + lo;
        bq[ct] = *(const short8*)(Bq + n * 64 + ((ks * 32 + hi * 8) ^ sw8(n)));
      }
#pragma unroll
      for (int rt = 0; rt < 2; rt++)
#pragma unroll
        for (int ct = 0; ct < 2; ct++)
          s[rt][ct] = __builtin_amdgcn_mfma_f32_16x16x32_bf16(
              ax[rt][ks], bq[ct], s[rt][ct], 0, 0, 0);
    }
    // exp + bias, stage P into per-wave LDS (D-layout -> A-layout transpose)
    float b0 = biasL[c0 + lo], b1 = biasL[c0 + 16 + lo];
#pragma unroll
    for (int rt = 0; rt < 2; rt++)
#pragma unroll
      for (int r = 0; r < 4; r++) {
        int prow = rt * 16 + hi * 4 + r;
        float e0 = __expf(s[rt][0][r] + b0);
        float e1 = __expf(s[rt][1][r] + b1);
        lsum[rt][r] += e0 + e1;
        Pw[prow * 64 + (lo ^ sw8(prow))] = (bf16)e0;
        Pw[prow * 64 + ((16 + lo) ^ sw8(prow))] = (bf16)e1;
      }
    // PV
    short8 ap[2];
#pragma unroll
    for (int rt = 0; rt < 2; rt++) {
      int prow = rt * 16 + lo;
      ap[rt] = *(const short8*)(Pw + prow * 64 + ((hi * 8) ^ sw8(prow)));
    }
#pragma unroll
    for (int dt = 0; dt < 4; dt++) {
      int d = dt * 16 + lo;
      short8 bv = *(const short8*)(BvT + d * VSTR + ((c0 + hi * 8) ^ sw8(d)));
#pragma unroll
      for (int rt = 0; rt < 2; rt++)
        accO[rt][dt] = __builtin_amdgcn_mfma_f32_16x16x32_bf16(
            ap[rt], bv, accO[rt][dt], 0, 0, 0);
    }
  }
}

__global__ __launch_bounds__(512)
void k_attn(const int* flagp, const float* __restrict__ Gk,
            const float* __restrict__ gb, const float* __restrict__ z,
            const float* __restrict__ ckq, const float* __restrict__ cqb,
            const float* __restrict__ cv, const bf16* __restrict__ xm,
            const void* smix, bf16* __restrict__ selfmid)
{
  __shared__ __attribute__((aligned(16))) bf16 GkB[64 * 64];    //  8 KiB
  __shared__ __attribute__((aligned(16))) bf16 zTB[64 * 64];    //  8 KiB
  __shared__ __attribute__((aligned(16))) bf16 ckqB[256 * 64];  // 32 KiB
  __shared__ __attribute__((aligned(16))) bf16 cvTB[64 * 256];  // 32 KiB
  __shared__ __attribute__((aligned(16))) bf16 Pst[8][32 * 64]; // 32 KiB
  __shared__ float cqbL[256];
  __shared__ float gbL[64];

  const int tid = threadIdx.x;
  const int bh = blockIdx.y, b = bh >> 3, h = bh & 7;

  // ---- stage (bf16 convert + swizzle; V matrices transposed to [d][s]) ----
  {
    int r = tid >> 3, c0 = (tid & 7) * 8;
    const float* g = Gk + ((size_t)(h * 64 + r)) * 64 + c0;
    bf16x8 v;
#pragma unroll
    for (int t = 0; t < 8; t++) v[t] = (bf16)g[t];
    *(bf16x8*)&GkB[r * 64 + (c0 ^ sw8(r))] = v;
    const float* zp = z + (size_t)bh * 4096 + (size_t)c0 * 64 + r;
#pragma unroll
    for (int t = 0; t < 8; t++) v[t] = (bf16)zp[t * 64];
    *(bf16x8*)&zTB[r * 64 + (c0 ^ sw8(r))] = v;
  }
#pragma unroll
  for (int rr = 0; rr < 4; rr++) {
    int idx = tid + rr * 512;
    int r = idx >> 3, c0 = (idx & 7) * 8;
    const float* c = ckq + (size_t)bh * 16384 + (size_t)r * 64 + c0;
    bf16x8 v;
#pragma unroll
    for (int t = 0; t < 8; t++) v[t] = (bf16)c[t];
    *(bf16x8*)&ckqB[r * 64 + (c0 ^ sw8(r))] = v;
  }
  {
    int d = tid >> 3, s0 = (tid & 7) * 32;
#pragma unroll
    for (int cc = 0; cc < 4; cc++) {
      int sb = s0 + cc * 8;
      bf16x8 v;
#pragma unroll
      for (int t = 0; t < 8; t++)
        v[t] = (bf16)cv[(size_t)bh * 16384 + (size_t)(sb + t) * 64 + d];
      *(bf16x8*)&cvTB[d * 256 + (sb ^ sw8(d))] = v;
    }
  }
  if (tid < 256)      cqbL[tid] = cqb[bh * 256 + tid];
  else if (tid < 320) gbL[tid - 256] = gb[h * 64 + (tid - 256)];
  __syncthreads();

  const int wid = tid >> 6, lane = tid & 63;
  const int lo = lane & 15, hi = lane >> 4;
  const int m0 = blockIdx.x * 256 + wid * 32;
  bf16* Pw = Pst[wid];

  // X A-frags (shared by self-QK and cross-QK): row = lane&15, k contiguous 8
  short8 ax[2][2];
#pragma unroll
  for (int rt = 0; rt < 2; rt++)
#pragma unroll
    for (int ks = 0; ks < 2; ks++)
      ax[rt][ks] = *(const short8*)(xm +
          (size_t)(b * 16384 + m0 + rt * 16 + lo) * 512 + h * 64 +
          ks * 32 + hi * 8);

  f32x4 accS[2][4], accC[2][4];
  float l1[2][4], l2[2][4];
#pragma unroll
  for (int rt = 0; rt < 2; rt++)
#pragma unroll
    for (int dt = 0; dt < 4; dt++) {
      accS[rt][dt] = f32x4{0.f, 0.f, 0.f, 0.f};
      accC[rt][dt] = f32x4{0.f, 0.f, 0.f, 0.f};
      l1[rt][dt] = 0.f;
      l2[rt][dt] = 0.f;
    }

  attn_part<2, 64>(GkB, zTB, gbL, ax, Pw, lo, hi, accS, l1);     // self (64 j)
  attn_part<8, 256>(ckqB, cvTB, cqbL, ax, Pw, lo, hi, accC, l2); // cross (256 s)

  // row-sum reduce across the 16 lanes holding the row's columns
#pragma unroll
  for (int rt = 0; rt < 2; rt++)
#pragma unroll
    for (int r = 0; r < 4; r++) {
      float a = l1[rt][r], c = l2[rt][r];
      for (int m = 1; m < 16; m <<= 1) {
        a += __shfl_xor(a, m);
        c += __shfl_xor(c, m);
      }
      l1[rt][r] = 1.f / a;
      l2[rt][r] = 1.f / c;
    }

  const int bf = *flagp;
  const float wmix = 1.f / (1.f + __expf(-ldf(smix, 0, bf)));
#pragma unroll
  for (int rt = 0; rt < 2; rt++)
#pragma unroll
    for (int r = 0; r < 4; r++) {
      int row = m0 + rt * 16 + hi * 4 + r;
      size_t off = (size_t)(b * 16384 + row) * 512 + h * 64;
#pragma unroll
      for (int dt = 0; dt < 4; dt++) {
        float vS = accS[rt][dt][r] * l1[rt][r];
        float vC = accC[rt][dt][r] * l2[rt][r];
        selfmid[off + dt * 16 + lo] = (bf16)(wmix * vS + (1.f - wmix) * vC);
      }
    }
}

// ---------------------------------------------------------------------------
extern "C" void kernel_launch(void* const* d_in, const int* in_sizes, int n_in,
                              void* d_out, int out_size, void* d_ws, size_t ws_size,
                              hipStream_t stream)
{
  const void* x    = d_in[0];
  const void* ctx  = d_in[1];
  const void* qg   = d_in[2];
  const void* Wp   = d_in[3];  const void* bp  = d_in[4];
  const void* Wk   = d_in[5];  const void* bk  = d_in[6];
  const void* Wv   = d_in[7];  const void* bv  = d_in[8];
  const void* Wcq  = d_in[9];  const void* bcq = d_in[10];
  const void* Wck  = d_in[11]; const void* bck = d_in[12];
  const void* Wcv  = d_in[13]; const void* bcv = d_in[14];
  const void* smix = d_in[15];
  const void* Wo   = d_in[16]; const void* bo  = d_in[17];

  char* ws = (char*)d_ws;
  int*   flag    = (int*)(ws);                   // 256 B reserved
  float* ck      = (float*)(ws + 256);           // 1,048,576 (dead after k_fold)
  float* cv      = (float*)(ws + 1048832);       // 1,048,576
  float* ckq     = (float*)(ws + 2097408);       // 1,048,576
  float* cqb     = (float*)(ws + 3145984);       // 16,384
  float* Gk      = (float*)(ws + 3162368);       // 131,072
  float* gb      = (float*)(ws + 3293440);       // 2,048
  float* lbuf    = (float*)(ws + 3295488);       // 4,096
  float* zpre    = (float*)(ws + 3299584);       // 1,048,576
  float* z       = (float*)(ws + 4348160);       // 1,048,576
  bf16*  xm      = (bf16*)(ws + 5396736);        // 33,554,432 (bf16)
  bf16*  selfmid = (bf16*)(ws + 38951168);       // 33,554,432 (bf16) -> ~69 MB
  // WpT/WoT reuse the ck region (dead after k_fold): 2 x 512 KiB bf16
  bf16*  WpT     = (bf16*)(ws + 256);
  bf16*  WoT     = (bf16*)(ws + 256 + 524288);

  k_detect<<<1, 64, 0, stream>>>(x, flag);

  k_ctx<<<1024, 256, 0, stream>>>(flag, ctx, Wck, bck, Wcv, bcv, ck, cv);
  k_fold<<<1152, 256, 0, stream>>>(flag, ck, Wcq, bcq, qg, Wk, bk,
                                   ckq, cqb, Gk, gb);

  // transpose+convert weights (overwrites ck, which is now dead)
  k_wtr<<<128, 256, 0, stream>>>(flag, Wp, Wo, WpT, WoT);

  // x_mid (flat (b,n,h*64+d), bf16) = x @ Wp + bp   [MFMA]
  k_gemm_mfma<<<dim3(4, 256), 256, 0, stream>>>(flag, x, 0, WpT, bp, xm, 0);

  k_stageA<<<dim3(16, 64), 256, 0, stream>>>(Gk, gb, xm, zpre, lbuf);
  k_znorm<<<16, 256, 0, stream>>>(flag, zpre, lbuf, Wv, bv, z);

  // merged MFMA self+cross attention + sigmoid mix -> selfmid
  k_attn<<<dim3(64, 16), 512, 0, stream>>>(flag, Gk, gb, z, ckq, cqb, cv, xm,
                                           smix, selfmid);

  // out = selfmid @ Wo + bo  (output dtype chosen by flag)   [MFMA]
  k_gemm_mfma<<<dim3(4, 256), 256, 0, stream>>>(flag, selfmid, 1, WoT, bo,
                                                d_out, 1);
}

// Round 3
// 469.920 us; speedup vs baseline: 3.4708x; 1.4727x over previous
//
#include <hip/hip_runtime.h>

typedef __bf16 bf16;
typedef __bf16 bf16x8 __attribute__((ext_vector_type(8)));
typedef short short8 __attribute__((ext_vector_type(8)));
typedef float f32x4 __attribute__((ext_vector_type(4)));

// Runtime-dual input loader: bf=1 -> buffer holds bf16, else f32.
__device__ __forceinline__ float ldf(const void* p, size_t i, int bf) {
  if (bf) {
    unsigned int u = ((const unsigned short*)p)[i];
    union { unsigned int ui; float f; } c;
    c.ui = u << 16;
    return c.f;
  }
  return ((const float*)p)[i];
}

// XOR swizzle for bf16 LDS tiles read as ds_read_b128 (16B chunks).
__device__ __forceinline__ int sw8(int r) { return ((r ^ (r >> 2)) & 7) << 3; }

// ---------------------------------------------------------------------------
// Dtype detector (unchanged).
// ---------------------------------------------------------------------------
__global__ void k_detect(const void* x, int* flag)
{
  int tid = threadIdx.x;  // 64 threads
  int cnt = 0;
  for (int j = 0; j < 4; j++) {
    int i = (tid * 4 + j) * 2;
    unsigned int u = ((const unsigned short*)x)[i];
    union { unsigned int ui; float f; } c;
    c.ui = u << 16;
    float a = fabsf(c.f);
    if (a >= 1e-4f && a <= 100.f) cnt++;
  }
  for (int m = 1; m < 64; m <<= 1) cnt += __shfl_xor(cnt, m);
  if (tid == 0) *flag = (cnt > 128) ? 1 : 0;
}

// ---------------------------------------------------------------------------
// ck/cv = context @ Wck/Wcv + bias   (4096 rows x 64) -> f32 internal
// ---------------------------------------------------------------------------
__global__ __launch_bounds__(256)
void k_ctx(const int* flagp, const void* ctx, const void* Wck, const void* bck,
           const void* Wcv, const void* bcv, float* __restrict__ ck,
           float* __restrict__ cv)
{
  const int bf = *flagp;
  int rid = blockIdx.x * 4 + (threadIdx.x >> 6);
  int dp = threadIdx.x & 63;
  float a1 = 0.f, a2 = 0.f;
  for (int e = 0; e < 64; e++) {
    float c = ldf(ctx, (size_t)rid * 64 + e, bf);
    a1 += c * ldf(Wck, e * 64 + dp, bf);
    a2 += c * ldf(Wcv, e * 64 + dp, bf);
  }
  ck[rid * 64 + dp] = a1 + ldf(bck, dp, bf);
  cv[rid * 64 + dp] = a2 + ldf(bcv, dp, bf);
}

// ---------------------------------------------------------------------------
// ckq[s][din] = Wcq-row(din) . ck[s] ; cqb[s] = bcq . ck[s]
// Gk[h*64+j][din] = Wk-row(din) . G[h][j] ; gb[h*64+j] = G[h][j] . bk
// ---------------------------------------------------------------------------
__global__ __launch_bounds__(256)
void k_fold(const int* flagp, const float* __restrict__ ck, const void* Wcq,
            const void* bcq, const void* qg, const void* Wk, const void* bk,
            float* __restrict__ ckq, float* __restrict__ cqb,
            float* __restrict__ Gk, float* __restrict__ gb)
{
  const int bf = *flagp;
  int bid = blockIdx.x, tid = threadIdx.x;
  if (bid < 1024) {
    int rid = bid * 4 + (tid >> 6), dp = tid & 63;
    const float* c = ck + (size_t)rid * 64;
    float a = 0.f;
    for (int o = 0; o < 64; o++) a += c[o] * ldf(Wcq, dp * 64 + o, bf);
    ckq[rid * 64 + dp] = a;
    if (dp == 0) {
      float s = 0.f;
      for (int o = 0; o < 64; o++) s += ldf(bcq, o, bf) * c[o];
      cqb[rid] = s;
    }
  } else {
    int i = (bid - 1024) * 256 + tid;    // [0, 32768)
    int row = i >> 6, dIn = i & 63;
    float s = 0.f;
    for (int d = 0; d < 64; d++)
      s += ldf(qg, (size_t)row * 64 + d, bf) * ldf(Wk, dIn * 64 + d, bf);
    Gk[i] = s;
    if (dIn == 0) {
      float t = 0.f;
      for (int d = 0; d < 64; d++)
        t += ldf(qg, (size_t)row * 64 + d, bf) * ldf(bk, d, bf);
      gb[row] = t;
    }
  }
}

// ---------------------------------------------------------------------------
// Weight prep: WT[n][k] = (bf16)W[k][n] for Wp (blocks 0..63) and Wo (64..127).
// ---------------------------------------------------------------------------
__global__ __launch_bounds__(256)
void k_wtr(const int* flagp, const void* Wp, const void* Wo,
           bf16* __restrict__ WpT, bf16* __restrict__ WoT)
{
  const int bf = *flagp;
  const int bid = blockIdx.x, tid = threadIdx.x;
  const void* W = (bid < 64) ? Wp : Wo;
  bf16* WT = (bid < 64) ? WpT : WoT;
  const int tb = bid & 63, kb = tb & 7, nb = tb >> 3;
  __shared__ float t[64][65];
  for (int e = tid; e < 4096; e += 256) {
    int k = e >> 6, n = e & 63;
    t[k][n] = ldf(W, (size_t)(kb * 64 + k) * 512 + nb * 64 + n, bf);
  }
  __syncthreads();
  for (int e = tid; e < 4096; e += 256) {
    int n = e >> 6, k = e & 63;
    WT[(size_t)(nb * 64 + n) * 512 + kb * 64 + k] = (bf16)t[k][n];
  }
}

// ---------------------------------------------------------------------------
// MFMA GEMM: out(Mx512) = A(Mx512) @ W(512x512) + bias, W given as WT[n][k] bf16.
// ---------------------------------------------------------------------------
__device__ __forceinline__ void g_stage(const void* A, int abf, const bf16* WT,
                                        int m0, int n0, int kt,
                                        bf16* __restrict__ As,
                                        bf16* __restrict__ Bs,
                                        int srow, int schk)
{
#pragma unroll
  for (int i = 0; i < 4; i++) {
    const int row = i * 32 + srow;
    const int koff = kt * 64 + schk * 8;
    bf16x8 v;
    if (abf) {
      v = *(const bf16x8*)((const bf16*)A + (size_t)(m0 + row) * 512 + koff);
    } else {
      const float* ap = (const float*)A + (size_t)(m0 + row) * 512 + koff;
      f32x4 f0 = *(const f32x4*)ap;
      f32x4 f1 = *(const f32x4*)(ap + 4);
#pragma unroll
      for (int j = 0; j < 4; j++) { v[j] = (bf16)f0[j]; v[4 + j] = (bf16)f1[j]; }
    }
    *(bf16x8*)&As[row * 64 + ((schk * 8) ^ sw8(row))] = v;
    bf16x8 w = *(const bf16x8*)(WT + (size_t)(n0 + row) * 512 + koff);
    *(bf16x8*)&Bs[row * 64 + ((schk * 8) ^ sw8(row))] = w;
  }
}

__global__ __launch_bounds__(256)
void k_gemm_mfma(const int* flagp, const void* A, const int amode,
                 const bf16* __restrict__ WT, const void* bias, void* out,
                 const int omode)
{
  __shared__ __attribute__((aligned(16))) bf16 AsB[2][128 * 64];
  __shared__ __attribute__((aligned(16))) bf16 BsB[2][128 * 64];

  const int bf = *flagp;
  const int abf = (amode == 1) || bf;
  const int tid = threadIdx.x;
  const int srow = tid >> 3, schk = tid & 7;
  const int m0 = blockIdx.y * 128, n0 = blockIdx.x * 128;

  const int lane = tid & 63, wid = tid >> 6;
  const int lo = lane & 15, hi = lane >> 4;
  const int wm = (wid >> 1) * 64, wn = (wid & 1) * 64;

  f32x4 acc[4][4];
#pragma unroll
  for (int mt = 0; mt < 4; mt++)
#pragma unroll
    for (int nt = 0; nt < 4; nt++) acc[mt][nt] = f32x4{0.f, 0.f, 0.f, 0.f};

  g_stage(A, abf, WT, m0, n0, 0, AsB[0], BsB[0], srow, schk);
  __syncthreads();

  int cur = 0;
  for (int kt = 0; kt < 8; kt++) {
    if (kt < 7)
      g_stage(A, abf, WT, m0, n0, kt + 1, AsB[cur ^ 1], BsB[cur ^ 1], srow, schk);
    const bf16* Asc = AsB[cur];
    const bf16* Bsc = BsB[cur];
#pragma unroll
    for (int ks = 0; ks < 2; ks++) {
      short8 af[4], bq[4];
#pragma unroll
      for (int mt = 0; mt < 4; mt++) {
        int r = wm + mt * 16 + lo;
        af[mt] = *(const short8*)&Asc[r * 64 + ((ks * 32 + hi * 8) ^ sw8(r))];
      }
#pragma unroll
      for (int nt = 0; nt < 4; nt++) {
        int r = wn + nt * 16 + lo;
        bq[nt] = *(const short8*)&Bsc[r * 64 + ((ks * 32 + hi * 8) ^ sw8(r))];
      }
#pragma unroll
      for (int mt = 0; mt < 4; mt++)
#pragma unroll
        for (int nt = 0; nt < 4; nt++)
          acc[mt][nt] = __builtin_amdgcn_mfma_f32_16x16x32_bf16(
              af[mt], bq[nt], acc[mt][nt], 0, 0, 0);
    }
    __syncthreads();
    cur ^= 1;
  }

#pragma unroll
  for (int nt = 0; nt < 4; nt++) {
    const int col = n0 + wn + nt * 16 + lo;
    const float bj = ldf(bias, col, bf);
#pragma unroll
    for (int mt = 0; mt < 4; mt++)
#pragma unroll
      for (int r = 0; r < 4; r++) {
        const int rowg = m0 + wm + mt * 16 + hi * 4 + r;
        const float v = acc[mt][nt][r] + bj;
        const size_t oi = (size_t)rowg * 512 + col;
        if (omode == 0 || bf) ((bf16*)out)[oi] = (bf16)v;
        else                  ((float*)out)[oi] = v;
      }
  }
}

// ---------------------------------------------------------------------------
// Stage B (MFMA): per (bh, token-split of 512):
//   S = Gk @ X^T (64 x 32 per tile), E = exp(S+gb)
//   zpart += E @ X (64x64), lpart += rowsum(E).
// 4 waves x 128 tokens, tiles of 32 tokens. E^T/X^T per-wave LDS staged
// (stride-64 rows, 32 used, sw8 swizzle -- the proven attn-P pattern).
// ---------------------------------------------------------------------------
__global__ __launch_bounds__(256, 2)
void k_stageB(const float* __restrict__ Gk, const float* __restrict__ gb,
              const bf16* __restrict__ xm, float* __restrict__ zpart,
              float* __restrict__ lpart)
{
  __shared__ __attribute__((aligned(16))) char smem[8192 + 65536 + 1024];
  bf16* GkB = (bf16*)smem;                       // 64x64 bf16, sw8
  const int tid = threadIdx.x;
  const int bh = blockIdx.y, b = bh >> 3, h = bh & 7;
  const int split = blockIdx.x;

  // stage Gk -> bf16 swizzled LDS
#pragma unroll
  for (int it = 0; it < 2; it++) {
    int idx = tid + it * 256;
    int r = idx >> 3, c0 = (idx & 7) * 8;
    const float* g = Gk + (size_t)(h * 64 + r) * 64 + c0;
    bf16x8 v;
#pragma unroll
    for (int t = 0; t < 8; t++) v[t] = (bf16)g[t];
    *(bf16x8*)&GkB[r * 64 + (c0 ^ sw8(r))] = v;
  }
  __syncthreads();

  const int wid = tid >> 6, lane = tid & 63;
  const int lo = lane & 15, hi = lane >> 4;
  bf16*  Ew  = (bf16*)(smem + 8192 + wid * 16384);          // [64][64] rows, 32 used
  short* Xts = (short*)(smem + 8192 + wid * 16384 + 8192);  // [64][64] rows, 32 used

  // Gk A-frags (reg-resident): rows j = jt*16+lo, k = ks*32+hi*8
  short8 gk[4][2];
#pragma unroll
  for (int jt = 0; jt < 4; jt++)
#pragma unroll
    for (int ks = 0; ks < 2; ks++) {
      int r = jt * 16 + lo;
      gk[jt][ks] = *(const short8*)&GkB[r * 64 + ((ks * 32 + hi * 8) ^ sw8(r))];
    }
  float gbl[4][4];
#pragma unroll
  for (int jt = 0; jt < 4; jt++)
#pragma unroll
    for (int r = 0; r < 4; r++)
      gbl[jt][r] = gb[h * 64 + jt * 16 + hi * 4 + r];

  f32x4 zacc[4][4];
  float lacc[4][4];
#pragma unroll
  for (int jt = 0; jt < 4; jt++)
#pragma unroll
    for (int q = 0; q < 4; q++) {
      zacc[jt][q] = f32x4{0.f, 0.f, 0.f, 0.f};
      lacc[jt][q] = 0.f;
    }

  const int tokbase = split * 512 + wid * 128;
  for (int t = 0; t < 4; t++) {
    const int t0 = tokbase + t * 32;
    // X B-frags direct from global: rows = tokens, k = dims
    short8 bx[2][2];
#pragma unroll
    for (int tt = 0; tt < 2; tt++)
#pragma unroll
      for (int ks = 0; ks < 2; ks++)
        bx[tt][ks] = *(const short8*)(xm +
            (size_t)(b * 16384 + t0 + tt * 16 + lo) * 512 + h * 64 +
            ks * 32 + hi * 8);
    // X^T staging: Xts[d][tok]
#pragma unroll
    for (int tt = 0; tt < 2; tt++)
#pragma unroll
      for (int ks = 0; ks < 2; ks++)
#pragma unroll
        for (int e = 0; e < 8; e++) {
          int d = ks * 32 + hi * 8 + e;
          int tok = tt * 16 + lo;
          Xts[d * 64 + (tok ^ sw8(d))] = bx[tt][ks][e];
        }
    // QK: D rows = j, cols = tok
    f32x4 s[4][2];
#pragma unroll
    for (int jt = 0; jt < 4; jt++)
#pragma unroll
      for (int tt = 0; tt < 2; tt++) s[jt][tt] = f32x4{0.f, 0.f, 0.f, 0.f};
#pragma unroll
    for (int ks = 0; ks < 2; ks++)
#pragma unroll
      for (int jt = 0; jt < 4; jt++)
#pragma unroll
        for (int tt = 0; tt < 2; tt++)
          s[jt][tt] = __builtin_amdgcn_mfma_f32_16x16x32_bf16(
              gk[jt][ks], bx[tt][ks], s[jt][tt], 0, 0, 0);
    // exp + l partial + E^T staging (D-layout -> A-layout)
#pragma unroll
    for (int jt = 0; jt < 4; jt++)
#pragma unroll
      for (int tt = 0; tt < 2; tt++)
#pragma unroll
        for (int r = 0; r < 4; r++) {
          int j = jt * 16 + hi * 4 + r;
          int tok = tt * 16 + lo;
          float e = __expf(s[jt][tt][r] + gbl[jt][r]);
          lacc[jt][r] += e;
          Ew[j * 64 + (tok ^ sw8(j))] = (bf16)e;
        }
    // E @ X via E^T A-frags x X^T B-frags (K = 32 tokens)
    short8 ea[4], xb[4];
#pragma unroll
    for (int jt = 0; jt < 4; jt++) {
      int r = jt * 16 + lo;
      ea[jt] = *(const short8*)&Ew[r * 64 + ((hi * 8) ^ sw8(r))];
    }
#pragma unroll
    for (int dt = 0; dt < 4; dt++) {
      int d = dt * 16 + lo;
      xb[dt] = *(const short8*)(Xts + d * 64 + ((hi * 8) ^ sw8(d)));
    }
#pragma unroll
    for (int jt = 0; jt < 4; jt++)
#pragma unroll
      for (int dt = 0; dt < 4; dt++)
        zacc[jt][dt] = __builtin_amdgcn_mfma_f32_16x16x32_bf16(
            ea[jt], xb[dt], zacc[jt][dt], 0, 0, 0);
  }

  // l: reduce over the 16 lanes (lo) holding a row's token columns
  float* lred = (float*)(smem + 8192 + 65536);
#pragma unroll
  for (int jt = 0; jt < 4; jt++)
#pragma unroll
    for (int r = 0; r < 4; r++) {
      float v = lacc[jt][r];
      for (int m = 1; m < 16; m <<= 1) v += __shfl_xor(v, m);
      if (lo == 0) lred[wid * 64 + jt * 16 + hi * 4 + r] = v;
    }
  __syncthreads();  // all waves done with Ew/Xts; safe to alias as f32 scratch

  float* zred = (float*)(smem + 8192);
#pragma unroll
  for (int jt = 0; jt < 4; jt++)
#pragma unroll
    for (int dt = 0; dt < 4; dt++)
#pragma unroll
      for (int r = 0; r < 4; r++)
        zred[wid * 4096 + (jt * 16 + hi * 4 + r) * 64 + dt * 16 + lo] =
            zacc[jt][dt][r];
  __syncthreads();

  const size_t pbase = ((size_t)bh * 32 + split) * 4096;
  for (int i = tid; i < 4096; i += 256)
    zpart[pbase + i] =
        zred[i] + zred[4096 + i] + zred[8192 + i] + zred[12288 + i];
  if (tid < 64)
    lpart[((size_t)bh * 32 + split) * 64 + tid] =
        lred[tid] + lred[64 + tid] + lred[128 + tid] + lred[192 + tid];
}

// z[bh][j][d] = (sum_split zpart / l_j) @ Wv[:,d] + bv[d]
__global__ __launch_bounds__(256)
void k_znorm(const int* flagp, const float* __restrict__ zpart,
             const float* __restrict__ lpart, const void* Wv, const void* bv,
             float* __restrict__ z)
{
  const int bf = *flagp;
  const int bh = blockIdx.x, tid = threadIdx.x;
  __shared__ float zsum[4096];
  __shared__ float lsum[64];
  for (int i = tid; i < 4096; i += 256) {
    float s = 0.f;
    for (int sp = 0; sp < 32; sp++)
      s += zpart[((size_t)bh * 32 + sp) * 4096 + i];
    zsum[i] = s;
  }
  if (tid < 64) {
    float s = 0.f;
    for (int sp = 0; sp < 32; sp++) s += lpart[((size_t)bh * 32 + sp) * 64 + tid];
    lsum[tid] = s;
  }
  __syncthreads();
  for (int i = tid; i < 4096; i += 256) {
    int j = i >> 6, d = i & 63;
    float inv = 1.f / lsum[j];
    float s = 0.f;
    for (int e = 0; e < 64; e++)
      s += zsum[j * 64 + e] * ldf(Wv, e * 64 + d, bf);
    z[(size_t)bh * 4096 + i] = s * inv + ldf(bv, d, bf);
  }
}

// ---------------------------------------------------------------------------
// Merged MFMA flash attention (self over 64 globals + cross over 256 ctx).
// ---------------------------------------------------------------------------
template <int NCH, int VSTR>
__device__ __forceinline__ void attn_part(
    const bf16* __restrict__ Bq, const bf16* __restrict__ BvT,
    const float* __restrict__ biasL, const short8 (&ax)[2][2],
    bf16* __restrict__ Pw, int lo, int hi,
    f32x4 (&accO)[2][4], float (&lsum)[2][4])
{
#pragma unroll
  for (int ch = 0; ch < NCH; ch++) {
    const int c0 = ch * 32;
    f32x4 s[2][2];
#pragma unroll
    for (int rt = 0; rt < 2; rt++)
#pragma unroll
      for (int ct = 0; ct < 2; ct++) s[rt][ct] = f32x4{0.f, 0.f, 0.f, 0.f};
#pragma unroll
    for (int ks = 0; ks < 2; ks++) {
      short8 bq[2];
#pragma unroll
      for (int ct = 0; ct < 2; ct++) {
        int n = c0 + ct * 16 + lo;
        bq[ct] = *(const short8*)(Bq + n * 64 + ((ks * 32 + hi * 8) ^ sw8(n)));
      }
#pragma unroll
      for (int rt = 0; rt < 2; rt++)
#pragma unroll
        for (int ct = 0; ct < 2; ct++)
          s[rt][ct] = __builtin_amdgcn_mfma_f32_16x16x32_bf16(
              ax[rt][ks], bq[ct], s[rt][ct], 0, 0, 0);
    }
    float b0 = biasL[c0 + lo], b1 = biasL[c0 + 16 + lo];
#pragma unroll
    for (int rt = 0; rt < 2; rt++)
#pragma unroll
      for (int r = 0; r < 4; r++) {
        int prow = rt * 16 + hi * 4 + r;
        float e0 = __expf(s[rt][0][r] + b0);
        float e1 = __expf(s[rt][1][r] + b1);
        lsum[rt][r] += e0 + e1;
        Pw[prow * 64 + (lo ^ sw8(prow))] = (bf16)e0;
        Pw[prow * 64 + ((16 + lo) ^ sw8(prow))] = (bf16)e1;
      }
    short8 ap[2];
#pragma unroll
    for (int rt = 0; rt < 2; rt++) {
      int prow = rt * 16 + lo;
      ap[rt] = *(const short8*)(Pw + prow * 64 + ((hi * 8) ^ sw8(prow)));
    }
#pragma unroll
    for (int dt = 0; dt < 4; dt++) {
      int d = dt * 16 + lo;
      short8 bv = *(const short8*)(BvT + d * VSTR + ((c0 + hi * 8) ^ sw8(d)));
#pragma unroll
      for (int rt = 0; rt < 2; rt++)
        accO[rt][dt] = __builtin_amdgcn_mfma_f32_16x16x32_bf16(
            ap[rt], bv, accO[rt][dt], 0, 0, 0);
    }
  }
}

__global__ __launch_bounds__(512)
void k_attn(const int* flagp, const float* __restrict__ Gk,
            const float* __restrict__ gb, const float* __restrict__ z,
            const float* __restrict__ ckq, const float* __restrict__ cqb,
            const float* __restrict__ cv, const bf16* __restrict__ xm,
            const void* smix, bf16* __restrict__ selfmid)
{
  __shared__ __attribute__((aligned(16))) bf16 GkB[64 * 64];
  __shared__ __attribute__((aligned(16))) bf16 zTB[64 * 64];
  __shared__ __attribute__((aligned(16))) bf16 ckqB[256 * 64];
  __shared__ __attribute__((aligned(16))) bf16 cvTB[64 * 256];
  __shared__ __attribute__((aligned(16))) bf16 Pst[8][32 * 64];
  __shared__ float cqbL[256];
  __shared__ float gbL[64];

  const int tid = threadIdx.x;
  const int bh = blockIdx.y, b = bh >> 3, h = bh & 7;

  {
    int r = tid >> 3, c0 = (tid & 7) * 8;
    const float* g = Gk + ((size_t)(h * 64 + r)) * 64 + c0;
    bf16x8 v;
#pragma unroll
    for (int t = 0; t < 8; t++) v[t] = (bf16)g[t];
    *(bf16x8*)&GkB[r * 64 + (c0 ^ sw8(r))] = v;
    const float* zp = z + (size_t)bh * 4096 + (size_t)c0 * 64 + r;
#pragma unroll
    for (int t = 0; t < 8; t++) v[t] = (bf16)zp[t * 64];
    *(bf16x8*)&zTB[r * 64 + (c0 ^ sw8(r))] = v;
  }
#pragma unroll
  for (int rr = 0; rr < 4; rr++) {
    int idx = tid + rr * 512;
    int r = idx >> 3, c0 = (idx & 7) * 8;
    const float* c = ckq + (size_t)bh * 16384 + (size_t)r * 64 + c0;
    bf16x8 v;
#pragma unroll
    for (int t = 0; t < 8; t++) v[t] = (bf16)c[t];
    *(bf16x8*)&ckqB[r * 64 + (c0 ^ sw8(r))] = v;
  }
  {
    int d = tid >> 3, s0 = (tid & 7) * 32;
#pragma unroll
    for (int cc = 0; cc < 4; cc++) {
      int sb = s0 + cc * 8;
      bf16x8 v;
#pragma unroll
      for (int t = 0; t < 8; t++)
        v[t] = (bf16)cv[(size_t)bh * 16384 + (size_t)(sb + t) * 64 + d];
      *(bf16x8*)&cvTB[d * 256 + (sb ^ sw8(d))] = v;
    }
  }
  if (tid < 256)      cqbL[tid] = cqb[bh * 256 + tid];
  else if (tid < 320) gbL[tid - 256] = gb[h * 64 + (tid - 256)];
  __syncthreads();

  const int wid = tid >> 6, lane = tid & 63;
  const int lo = lane & 15, hi = lane >> 4;
  const int m0 = blockIdx.x * 256 + wid * 32;
  bf16* Pw = Pst[wid];

  short8 ax[2][2];
#pragma unroll
  for (int rt = 0; rt < 2; rt++)
#pragma unroll
    for (int ks = 0; ks < 2; ks++)
      ax[rt][ks] = *(const short8*)(xm +
          (size_t)(b * 16384 + m0 + rt * 16 + lo) * 512 + h * 64 +
          ks * 32 + hi * 8);

  f32x4 accS[2][4], accC[2][4];
  float l1[2][4], l2[2][4];
#pragma unroll
  for (int rt = 0; rt < 2; rt++)
#pragma unroll
    for (int dt = 0; dt < 4; dt++) {
      accS[rt][dt] = f32x4{0.f, 0.f, 0.f, 0.f};
      accC[rt][dt] = f32x4{0.f, 0.f, 0.f, 0.f};
      l1[rt][dt] = 0.f;
      l2[rt][dt] = 0.f;
    }

  attn_part<2, 64>(GkB, zTB, gbL, ax, Pw, lo, hi, accS, l1);
  attn_part<8, 256>(ckqB, cvTB, cqbL, ax, Pw, lo, hi, accC, l2);

#pragma unroll
  for (int rt = 0; rt < 2; rt++)
#pragma unroll
    for (int r = 0; r < 4; r++) {
      float a = l1[rt][r], c = l2[rt][r];
      for (int m = 1; m < 16; m <<= 1) {
        a += __shfl_xor(a, m);
        c += __shfl_xor(c, m);
      }
      l1[rt][r] = 1.f / a;
      l2[rt][r] = 1.f / c;
    }

  const int bf = *flagp;
  const float wmix = 1.f / (1.f + __expf(-ldf(smix, 0, bf)));
#pragma unroll
  for (int rt = 0; rt < 2; rt++)
#pragma unroll
    for (int r = 0; r < 4; r++) {
      int row = m0 + rt * 16 + hi * 4 + r;
      size_t off = (size_t)(b * 16384 + row) * 512 + h * 64;
#pragma unroll
      for (int dt = 0; dt < 4; dt++) {
        float vS = accS[rt][dt][r] * l1[rt][r];
        float vC = accC[rt][dt][r] * l2[rt][r];
        selfmid[off + dt * 16 + lo] = (bf16)(wmix * vS + (1.f - wmix) * vC);
      }
    }
}

// ---------------------------------------------------------------------------
extern "C" void kernel_launch(void* const* d_in, const int* in_sizes, int n_in,
                              void* d_out, int out_size, void* d_ws, size_t ws_size,
                              hipStream_t stream)
{
  const void* x    = d_in[0];
  const void* ctx  = d_in[1];
  const void* qg   = d_in[2];
  const void* Wp   = d_in[3];  const void* bp  = d_in[4];
  const void* Wk   = d_in[5];  const void* bk  = d_in[6];
  const void* Wv   = d_in[7];  const void* bv  = d_in[8];
  const void* Wcq  = d_in[9];  const void* bcq = d_in[10];
  const void* Wck  = d_in[11]; const void* bck = d_in[12];
  const void* Wcv  = d_in[13]; const void* bcv = d_in[14];
  const void* smix = d_in[15];
  const void* Wo   = d_in[16]; const void* bo  = d_in[17];

  char* ws = (char*)d_ws;
  int*   flag    = (int*)(ws);                   // 256 B reserved
  float* ck      = (float*)(ws + 256);           // 1,048,576 (dead after k_fold)
  float* cv      = (float*)(ws + 1048832);       // 1,048,576
  float* ckq     = (float*)(ws + 2097408);       // 1,048,576
  float* cqb     = (float*)(ws + 3145984);       // 16,384
  float* Gk      = (float*)(ws + 3162368);       // 131,072
  float* gb      = (float*)(ws + 3293440);       // 2,048
  float* z       = (float*)(ws + 4348160);       // 1,048,576
  bf16*  xm      = (bf16*)(ws + 5396736);        // 33,554,432 (bf16)
  bf16*  selfmid = (bf16*)(ws + 38951168);       // 33,554,432 (bf16)
  // WpT/WoT reuse the ck region (dead after k_fold)
  bf16*  WpT     = (bf16*)(ws + 256);
  bf16*  WoT     = (bf16*)(ws + 256 + 524288);
  // zpart/lpart park in the selfmid region (dead until k_attn, which runs
  // after k_znorm has consumed them): 8 MB + 128 KB
  float* zpart   = (float*)(ws + 38951168);
  float* lpart   = (float*)(ws + 38951168 + 8388608);

  k_detect<<<1, 64, 0, stream>>>(x, flag);

  k_ctx<<<1024, 256, 0, stream>>>(flag, ctx, Wck, bck, Wcv, bcv, ck, cv);
  k_fold<<<1152, 256, 0, stream>>>(flag, ck, Wcq, bcq, qg, Wk, bk,
                                   ckq, cqb, Gk, gb);

  k_wtr<<<128, 256, 0, stream>>>(flag, Wp, Wo, WpT, WoT);

  // x_mid (flat (b,n,h*64+d), bf16) = x @ Wp + bp   [MFMA]
  k_gemm_mfma<<<dim3(4, 256), 256, 0, stream>>>(flag, x, 0, WpT, bp, xm, 0);

  // z partials via MFMA split-K over tokens
  k_stageB<<<dim3(32, 16), 256, 0, stream>>>(Gk, gb, xm, zpart, lpart);
  k_znorm<<<16, 256, 0, stream>>>(flag, zpart, lpart, Wv, bv, z);

  // merged MFMA self+cross attention + sigmoid mix -> selfmid
  k_attn<<<dim3(64, 16), 512, 0, stream>>>(flag, Gk, gb, z, ckq, cqb, cv, xm,
                                           smix, selfmid);

  // out = selfmid @ Wo + bo  (output dtype chosen by flag)   [MFMA]
  k_gemm_mfma<<<dim3(4, 256), 256, 0, stream>>>(flag, selfmid, 1, WoT, bo,
                                                d_out, 1);
}

// Round 4
// 432.973 us; speedup vs baseline: 3.7670x; 1.0853x over previous
//
#include <hip/hip_runtime.h>

typedef __bf16 bf16;
typedef __bf16 bf16x8 __attribute__((ext_vector_type(8)));
typedef short short8 __attribute__((ext_vector_type(8)));
typedef float f32x4 __attribute__((ext_vector_type(4)));

// Runtime-dual input loader: bf=1 -> buffer holds bf16, else f32.
__device__ __forceinline__ float ldf(const void* p, size_t i, int bf) {
  if (bf) {
    unsigned int u = ((const unsigned short*)p)[i];
    union { unsigned int ui; float f; } c;
    c.ui = u << 16;
    return c.f;
  }
  return ((const float*)p)[i];
}

// XOR swizzle for bf16 LDS tiles read as ds_read_b128 (16B chunks).
__device__ __forceinline__ int sw8(int r) { return ((r ^ (r >> 2)) & 7) << 3; }

// ---------------------------------------------------------------------------
// Dtype detector (unchanged).
// ---------------------------------------------------------------------------
__global__ void k_detect(const void* x, int* flag)
{
  int tid = threadIdx.x;  // 64 threads
  int cnt = 0;
  for (int j = 0; j < 4; j++) {
    int i = (tid * 4 + j) * 2;
    unsigned int u = ((const unsigned short*)x)[i];
    union { unsigned int ui; float f; } c;
    c.ui = u << 16;
    float a = fabsf(c.f);
    if (a >= 1e-4f && a <= 100.f) cnt++;
  }
  for (int m = 1; m < 64; m <<= 1) cnt += __shfl_xor(cnt, m);
  if (tid == 0) *flag = (cnt > 128) ? 1 : 0;
}

// ---------------------------------------------------------------------------
// ck/cv = context @ Wck/Wcv + bias   (4096 rows x 64) -> f32 internal
// ---------------------------------------------------------------------------
__global__ __launch_bounds__(256)
void k_ctx(const int* flagp, const void* ctx, const void* Wck, const void* bck,
           const void* Wcv, const void* bcv, float* __restrict__ ck,
           float* __restrict__ cv)
{
  const int bf = *flagp;
  int rid = blockIdx.x * 4 + (threadIdx.x >> 6);
  int dp = threadIdx.x & 63;
  float a1 = 0.f, a2 = 0.f;
  for (int e = 0; e < 64; e++) {
    float c = ldf(ctx, (size_t)rid * 64 + e, bf);
    a1 += c * ldf(Wck, e * 64 + dp, bf);
    a2 += c * ldf(Wcv, e * 64 + dp, bf);
  }
  ck[rid * 64 + dp] = a1 + ldf(bck, dp, bf);
  cv[rid * 64 + dp] = a2 + ldf(bcv, dp, bf);
}

// ---------------------------------------------------------------------------
// ckq[s][din] = Wcq-row(din) . ck[s] ; cqb[s] = bcq . ck[s]
// Gk[h*64+j][din] = Wk-row(din) . G[h][j] ; gb[h*64+j] = G[h][j] . bk
// ---------------------------------------------------------------------------
__global__ __launch_bounds__(256)
void k_fold(const int* flagp, const float* __restrict__ ck, const void* Wcq,
            const void* bcq, const void* qg, const void* Wk, const void* bk,
            float* __restrict__ ckq, float* __restrict__ cqb,
            float* __restrict__ Gk, float* __restrict__ gb)
{
  const int bf = *flagp;
  int bid = blockIdx.x, tid = threadIdx.x;
  if (bid < 1024) {
    int rid = bid * 4 + (tid >> 6), dp = tid & 63;
    const float* c = ck + (size_t)rid * 64;
    float a = 0.f;
    for (int o = 0; o < 64; o++) a += c[o] * ldf(Wcq, dp * 64 + o, bf);
    ckq[rid * 64 + dp] = a;
    if (dp == 0) {
      float s = 0.f;
      for (int o = 0; o < 64; o++) s += ldf(bcq, o, bf) * c[o];
      cqb[rid] = s;
    }
  } else {
    int i = (bid - 1024) * 256 + tid;    // [0, 32768)
    int row = i >> 6, dIn = i & 63;
    float s = 0.f;
    for (int d = 0; d < 64; d++)
      s += ldf(qg, (size_t)row * 64 + d, bf) * ldf(Wk, dIn * 64 + d, bf);
    Gk[i] = s;
    if (dIn == 0) {
      float t = 0.f;
      for (int d = 0; d < 64; d++)
        t += ldf(qg, (size_t)row * 64 + d, bf) * ldf(bk, d, bf);
      gb[row] = t;
    }
  }
}

// ---------------------------------------------------------------------------
// Weight prep: WT[n][k] = (bf16)W[k][n] for Wp (blocks 0..63) and Wo (64..127).
// ---------------------------------------------------------------------------
__global__ __launch_bounds__(256)
void k_wtr(const int* flagp, const void* Wp, const void* Wo,
           bf16* __restrict__ WpT, bf16* __restrict__ WoT)
{
  const int bf = *flagp;
  const int bid = blockIdx.x, tid = threadIdx.x;
  const void* W = (bid < 64) ? Wp : Wo;
  bf16* WT = (bid < 64) ? WpT : WoT;
  const int tb = bid & 63, kb = tb & 7, nb = tb >> 3;
  __shared__ float t[64][65];
  for (int e = tid; e < 4096; e += 256) {
    int k = e >> 6, n = e & 63;
    t[k][n] = ldf(W, (size_t)(kb * 64 + k) * 512 + nb * 64 + n, bf);
  }
  __syncthreads();
  for (int e = tid; e < 4096; e += 256) {
    int n = e >> 6, k = e & 63;
    WT[(size_t)(nb * 64 + n) * 512 + kb * 64 + k] = (bf16)t[k][n];
  }
}

// ---------------------------------------------------------------------------
// MFMA GEMM: out(Mx512) = A(Mx512) @ W(512x512) + bias, W given as WT[n][k] bf16.
// 128x128 tile, BK=64, 4 waves. T14 async-stage split: global->regs issued at
// top of each K-iter, regs->LDS written AFTER the compute phase (vmcnt wait
// hides under MFMA+ds_read). Double-buffered LDS, ONE barrier per K-iter.
// T1 bijective XCD swizzle: each XCD owns a contiguous run of m-tiles.
// ---------------------------------------------------------------------------
__global__ __launch_bounds__(256)
void k_gemm_mfma(const int* flagp, const void* A, const int amode,
                 const bf16* __restrict__ WT, const void* bias, void* out,
                 const int omode)
{
  __shared__ __attribute__((aligned(16))) bf16 AsB[2][128 * 64];
  __shared__ __attribute__((aligned(16))) bf16 BsB[2][128 * 64];

  const int bf = *flagp;
  const int abf = (amode == 1) || bf;
  const int tid = threadIdx.x;
  const int srow = tid >> 3, schk = tid & 7;

  // XCD swizzle (grid = 4 x 256 -> 1024 blocks, 1024 % 8 == 0: bijective).
  const int orig = blockIdx.y * 4 + blockIdx.x;
  const int nid = (orig & 7) * 128 + (orig >> 3);
  const int m0 = (nid >> 2) * 128, n0 = (nid & 3) * 128;

  const int lane = tid & 63, wid = tid >> 6;
  const int lo = lane & 15, hi = lane >> 4;
  const int wm = (wid >> 1) * 64, wn = (wid & 1) * 64;

  // staging registers (f32 path keeps raw f32; cvt deferred to LDS-write time)
  f32x4 rf[4][2];
  bf16x8 rb[4];
  bf16x8 rw[4];

  auto ldreg = [&](int kt) {
    const int koff = kt * 64 + schk * 8;
#pragma unroll
    for (int i = 0; i < 4; i++) {
      const int row = i * 32 + srow;
      if (abf) {
        rb[i] = *(const bf16x8*)((const bf16*)A + (size_t)(m0 + row) * 512 + koff);
      } else {
        const float* ap = (const float*)A + (size_t)(m0 + row) * 512 + koff;
        rf[i][0] = *(const f32x4*)ap;
        rf[i][1] = *(const f32x4*)(ap + 4);
      }
      rw[i] = *(const bf16x8*)(WT + (size_t)(n0 + row) * 512 + koff);
    }
  };
  auto stlds = [&](bf16* As, bf16* Bs) {
    const int c = schk * 8;
#pragma unroll
    for (int i = 0; i < 4; i++) {
      const int row = i * 32 + srow;
      bf16x8 v;
      if (abf) {
        v = rb[i];
      } else {
#pragma unroll
        for (int j = 0; j < 4; j++) {
          v[j] = (bf16)rf[i][0][j];
          v[4 + j] = (bf16)rf[i][1][j];
        }
      }
      *(bf16x8*)&As[row * 64 + (c ^ sw8(row))] = v;
      *(bf16x8*)&Bs[row * 64 + (c ^ sw8(row))] = rw[i];
    }
  };

  f32x4 acc[4][4];
#pragma unroll
  for (int mt = 0; mt < 4; mt++)
#pragma unroll
    for (int nt = 0; nt < 4; nt++) acc[mt][nt] = f32x4{0.f, 0.f, 0.f, 0.f};

  ldreg(0);
  stlds(AsB[0], BsB[0]);
  __syncthreads();

  int cur = 0;
  for (int kt = 0; kt < 8; kt++) {
    if (kt < 7) ldreg(kt + 1);          // issue next-tile loads (in flight)
    const bf16* Asc = AsB[cur];
    const bf16* Bsc = BsB[cur];
#pragma unroll
    for (int ks = 0; ks < 2; ks++) {
      short8 af[4], bq[4];
#pragma unroll
      for (int mt = 0; mt < 4; mt++) {
        int r = wm + mt * 16 + lo;
        af[mt] = *(const short8*)&Asc[r * 64 + ((ks * 32 + hi * 8) ^ sw8(r))];
      }
#pragma unroll
      for (int nt = 0; nt < 4; nt++) {
        int r = wn + nt * 16 + lo;
        bq[nt] = *(const short8*)&Bsc[r * 64 + ((ks * 32 + hi * 8) ^ sw8(r))];
      }
#pragma unroll
      for (int mt = 0; mt < 4; mt++)
#pragma unroll
        for (int nt = 0; nt < 4; nt++)
          acc[mt][nt] = __builtin_amdgcn_mfma_f32_16x16x32_bf16(
              af[mt], bq[nt], acc[mt][nt], 0, 0, 0);
    }
    if (kt < 7) stlds(AsB[cur ^ 1], BsB[cur ^ 1]);  // vmcnt hidden by compute
    __syncthreads();
    cur ^= 1;
  }

#pragma unroll
  for (int nt = 0; nt < 4; nt++) {
    const int col = n0 + wn + nt * 16 + lo;
    const float bj = ldf(bias, col, bf);
#pragma unroll
    for (int mt = 0; mt < 4; mt++)
#pragma unroll
      for (int r = 0; r < 4; r++) {
        const int rowg = m0 + wm + mt * 16 + hi * 4 + r;
        const float v = acc[mt][nt][r] + bj;
        const size_t oi = (size_t)rowg * 512 + col;
        if (omode == 0 || bf) ((bf16*)out)[oi] = (bf16)v;
        else                  ((float*)out)[oi] = v;
      }
  }
}

// ---------------------------------------------------------------------------
// Stage B (MFMA): per (bh, token-split of 512):
//   S = Gk @ X^T (64 x 32 per tile), E = exp(S+gb)
//   zpart += E @ X (64x64), lpart += rowsum(E).
// ---------------------------------------------------------------------------
__global__ __launch_bounds__(256, 2)
void k_stageB(const float* __restrict__ Gk, const float* __restrict__ gb,
              const bf16* __restrict__ xm, float* __restrict__ zpart,
              float* __restrict__ lpart)
{
  __shared__ __attribute__((aligned(16))) char smem[8192 + 65536 + 1024];
  bf16* GkB = (bf16*)smem;                       // 64x64 bf16, sw8
  const int tid = threadIdx.x;
  const int bh = blockIdx.y, b = bh >> 3, h = bh & 7;
  const int split = blockIdx.x;

#pragma unroll
  for (int it = 0; it < 2; it++) {
    int idx = tid + it * 256;
    int r = idx >> 3, c0 = (idx & 7) * 8;
    const float* g = Gk + (size_t)(h * 64 + r) * 64 + c0;
    bf16x8 v;
#pragma unroll
    for (int t = 0; t < 8; t++) v[t] = (bf16)g[t];
    *(bf16x8*)&GkB[r * 64 + (c0 ^ sw8(r))] = v;
  }
  __syncthreads();

  const int wid = tid >> 6, lane = tid & 63;
  const int lo = lane & 15, hi = lane >> 4;
  bf16*  Ew  = (bf16*)(smem + 8192 + wid * 16384);
  short* Xts = (short*)(smem + 8192 + wid * 16384 + 8192);

  short8 gk[4][2];
#pragma unroll
  for (int jt = 0; jt < 4; jt++)
#pragma unroll
    for (int ks = 0; ks < 2; ks++) {
      int r = jt * 16 + lo;
      gk[jt][ks] = *(const short8*)&GkB[r * 64 + ((ks * 32 + hi * 8) ^ sw8(r))];
    }
  float gbl[4][4];
#pragma unroll
  for (int jt = 0; jt < 4; jt++)
#pragma unroll
    for (int r = 0; r < 4; r++)
      gbl[jt][r] = gb[h * 64 + jt * 16 + hi * 4 + r];

  f32x4 zacc[4][4];
  float lacc[4][4];
#pragma unroll
  for (int jt = 0; jt < 4; jt++)
#pragma unroll
    for (int q = 0; q < 4; q++) {
      zacc[jt][q] = f32x4{0.f, 0.f, 0.f, 0.f};
      lacc[jt][q] = 0.f;
    }

  const int tokbase = split * 512 + wid * 128;
  for (int t = 0; t < 4; t++) {
    const int t0 = tokbase + t * 32;
    short8 bx[2][2];
#pragma unroll
    for (int tt = 0; tt < 2; tt++)
#pragma unroll
      for (int ks = 0; ks < 2; ks++)
        bx[tt][ks] = *(const short8*)(xm +
            (size_t)(b * 16384 + t0 + tt * 16 + lo) * 512 + h * 64 +
            ks * 32 + hi * 8);
#pragma unroll
    for (int tt = 0; tt < 2; tt++)
#pragma unroll
      for (int ks = 0; ks < 2; ks++)
#pragma unroll
        for (int e = 0; e < 8; e++) {
          int d = ks * 32 + hi * 8 + e;
          int tok = tt * 16 + lo;
          Xts[d * 64 + (tok ^ sw8(d))] = bx[tt][ks][e];
        }
    f32x4 s[4][2];
#pragma unroll
    for (int jt = 0; jt < 4; jt++)
#pragma unroll
      for (int tt = 0; tt < 2; tt++) s[jt][tt] = f32x4{0.f, 0.f, 0.f, 0.f};
#pragma unroll
    for (int ks = 0; ks < 2; ks++)
#pragma unroll
      for (int jt = 0; jt < 4; jt++)
#pragma unroll
        for (int tt = 0; tt < 2; tt++)
          s[jt][tt] = __builtin_amdgcn_mfma_f32_16x16x32_bf16(
              gk[jt][ks], bx[tt][ks], s[jt][tt], 0, 0, 0);
#pragma unroll
    for (int jt = 0; jt < 4; jt++)
#pragma unroll
      for (int tt = 0; tt < 2; tt++)
#pragma unroll
        for (int r = 0; r < 4; r++) {
          int j = jt * 16 + hi * 4 + r;
          int tok = tt * 16 + lo;
          float e = __expf(s[jt][tt][r] + gbl[jt][r]);
          lacc[jt][r] += e;
          Ew[j * 64 + (tok ^ sw8(j))] = (bf16)e;
        }
    short8 ea[4], xb[4];
#pragma unroll
    for (int jt = 0; jt < 4; jt++) {
      int r = jt * 16 + lo;
      ea[jt] = *(const short8*)&Ew[r * 64 + ((hi * 8) ^ sw8(r))];
    }
#pragma unroll
    for (int dt = 0; dt < 4; dt++) {
      int d = dt * 16 + lo;
      xb[dt] = *(const short8*)(Xts + d * 64 + ((hi * 8) ^ sw8(d)));
    }
#pragma unroll
    for (int jt = 0; jt < 4; jt++)
#pragma unroll
      for (int dt = 0; dt < 4; dt++)
        zacc[jt][dt] = __builtin_amdgcn_mfma_f32_16x16x32_bf16(
            ea[jt], xb[dt], zacc[jt][dt], 0, 0, 0);
  }

  float* lred = (float*)(smem + 8192 + 65536);
#pragma unroll
  for (int jt = 0; jt < 4; jt++)
#pragma unroll
    for (int r = 0; r < 4; r++) {
      float v = lacc[jt][r];
      for (int m = 1; m < 16; m <<= 1) v += __shfl_xor(v, m);
      if (lo == 0) lred[wid * 64 + jt * 16 + hi * 4 + r] = v;
    }
  __syncthreads();

  float* zred = (float*)(smem + 8192);
#pragma unroll
  for (int jt = 0; jt < 4; jt++)
#pragma unroll
    for (int dt = 0; dt < 4; dt++)
#pragma unroll
      for (int r = 0; r < 4; r++)
        zred[wid * 4096 + (jt * 16 + hi * 4 + r) * 64 + dt * 16 + lo] =
            zacc[jt][dt][r];
  __syncthreads();

  const size_t pbase = ((size_t)bh * 32 + split) * 4096;
  for (int i = tid; i < 4096; i += 256)
    zpart[pbase + i] =
        zred[i] + zred[4096 + i] + zred[8192 + i] + zred[12288 + i];
  if (tid < 64)
    lpart[((size_t)bh * 32 + split) * 64 + tid] =
        lred[tid] + lred[64 + tid] + lred[128 + tid] + lred[192 + tid];
}

// z[bh][j][d] = (sum_split zpart / l_j) @ Wv[:,d] + bv[d]
__global__ __launch_bounds__(256)
void k_znorm(const int* flagp, const float* __restrict__ zpart,
             const float* __restrict__ lpart, const void* Wv, const void* bv,
             float* __restrict__ z)
{
  const int bf = *flagp;
  const int bh = blockIdx.x, tid = threadIdx.x;
  __shared__ float zsum[4096];
  __shared__ float lsum[64];
  for (int i = tid; i < 4096; i += 256) {
    float s = 0.f;
    for (int sp = 0; sp < 32; sp++)
      s += zpart[((size_t)bh * 32 + sp) * 4096 + i];
    zsum[i] = s;
  }
  if (tid < 64) {
    float s = 0.f;
    for (int sp = 0; sp < 32; sp++) s += lpart[((size_t)bh * 32 + sp) * 64 + tid];
    lsum[tid] = s;
  }
  __syncthreads();
  for (int i = tid; i < 4096; i += 256) {
    int j = i >> 6, d = i & 63;
    float inv = 1.f / lsum[j];
    float s = 0.f;
    for (int e = 0; e < 64; e++)
      s += zsum[j * 64 + e] * ldf(Wv, e * 64 + d, bf);
    z[(size_t)bh * 4096 + i] = s * inv + ldf(bv, d, bf);
  }
}

// ---------------------------------------------------------------------------
// Merged MFMA flash attention (self over 64 globals + cross over 256 ctx).
// ---------------------------------------------------------------------------
template <int NCH, int VSTR>
__device__ __forceinline__ void attn_part(
    const bf16* __restrict__ Bq, const bf16* __restrict__ BvT,
    const float* __restrict__ biasL, const short8 (&ax)[2][2],
    bf16* __restrict__ Pw, int lo, int hi,
    f32x4 (&accO)[2][4], float (&lsum)[2][4])
{
#pragma unroll
  for (int ch = 0; ch < NCH; ch++) {
    const int c0 = ch * 32;
    f32x4 s[2][2];
#pragma unroll
    for (int rt = 0; rt < 2; rt++)
#pragma unroll
      for (int ct = 0; ct < 2; ct++) s[rt][ct] = f32x4{0.f, 0.f, 0.f, 0.f};
#pragma unroll
    for (int ks = 0; ks < 2; ks++) {
      short8 bq[2];
#pragma unroll
      for (int ct = 0; ct < 2; ct++) {
        int n = c0 + ct * 16 + lo;
        bq[ct] = *(const short8*)(Bq + n * 64 + ((ks * 32 + hi * 8) ^ sw8(n)));
      }
#pragma unroll
      for (int rt = 0; rt < 2; rt++)
#pragma unroll
        for (int ct = 0; ct < 2; ct++)
          s[rt][ct] = __builtin_amdgcn_mfma_f32_16x16x32_bf16(
              ax[rt][ks], bq[ct], s[rt][ct], 0, 0, 0);
    }
    float b0 = biasL[c0 + lo], b1 = biasL[c0 + 16 + lo];
#pragma unroll
    for (int rt = 0; rt < 2; rt++)
#pragma unroll
      for (int r = 0; r < 4; r++) {
        int prow = rt * 16 + hi * 4 + r;
        float e0 = __expf(s[rt][0][r] + b0);
        float e1 = __expf(s[rt][1][r] + b1);
        lsum[rt][r] += e0 + e1;
        Pw[prow * 64 + (lo ^ sw8(prow))] = (bf16)e0;
        Pw[prow * 64 + ((16 + lo) ^ sw8(prow))] = (bf16)e1;
      }
    short8 ap[2];
#pragma unroll
    for (int rt = 0; rt < 2; rt++) {
      int prow = rt * 16 + lo;
      ap[rt] = *(const short8*)(Pw + prow * 64 + ((hi * 8) ^ sw8(prow)));
    }
#pragma unroll
    for (int dt = 0; dt < 4; dt++) {
      int d = dt * 16 + lo;
      short8 bv = *(const short8*)(BvT + d * VSTR + ((c0 + hi * 8) ^ sw8(d)));
#pragma unroll
      for (int rt = 0; rt < 2; rt++)
        accO[rt][dt] = __builtin_amdgcn_mfma_f32_16x16x32_bf16(
            ap[rt], bv, accO[rt][dt], 0, 0, 0);
    }
  }
}

__global__ __launch_bounds__(512)
void k_attn(const int* flagp, const float* __restrict__ Gk,
            const float* __restrict__ gb, const float* __restrict__ z,
            const float* __restrict__ ckq, const float* __restrict__ cqb,
            const float* __restrict__ cv, const bf16* __restrict__ xm,
            const void* smix, bf16* __restrict__ selfmid)
{
  __shared__ __attribute__((aligned(16))) bf16 GkB[64 * 64];
  __shared__ __attribute__((aligned(16))) bf16 zTB[64 * 64];
  __shared__ __attribute__((aligned(16))) bf16 ckqB[256 * 64];
  __shared__ __attribute__((aligned(16))) bf16 cvTB[64 * 256];
  __shared__ __attribute__((aligned(16))) bf16 Pst[8][32 * 64];
  __shared__ float cqbL[256];
  __shared__ float gbL[64];

  const int tid = threadIdx.x;
  const int bh = blockIdx.y, b = bh >> 3, h = bh & 7;

  {
    int r = tid >> 3, c0 = (tid & 7) * 8;
    const float* g = Gk + ((size_t)(h * 64 + r)) * 64 + c0;
    bf16x8 v;
#pragma unroll
    for (int t = 0; t < 8; t++) v[t] = (bf16)g[t];
    *(bf16x8*)&GkB[r * 64 + (c0 ^ sw8(r))] = v;
    const float* zp = z + (size_t)bh * 4096 + (size_t)c0 * 64 + r;
#pragma unroll
    for (int t = 0; t < 8; t++) v[t] = (bf16)zp[t * 64];
    *(bf16x8*)&zTB[r * 64 + (c0 ^ sw8(r))] = v;
  }
#pragma unroll
  for (int rr = 0; rr < 4; rr++) {
    int idx = tid + rr * 512;
    int r = idx >> 3, c0 = (idx & 7) * 8;
    const float* c = ckq + (size_t)bh * 16384 + (size_t)r * 64 + c0;
    bf16x8 v;
#pragma unroll
    for (int t = 0; t < 8; t++) v[t] = (bf16)c[t];
    *(bf16x8*)&ckqB[r * 64 + (c0 ^ sw8(r))] = v;
  }
  {
    int d = tid >> 3, s0 = (tid & 7) * 32;
#pragma unroll
    for (int cc = 0; cc < 4; cc++) {
      int sb = s0 + cc * 8;
      bf16x8 v;
#pragma unroll
      for (int t = 0; t < 8; t++)
        v[t] = (bf16)cv[(size_t)bh * 16384 + (size_t)(sb + t) * 64 + d];
      *(bf16x8*)&cvTB[d * 256 + (sb ^ sw8(d))] = v;
    }
  }
  if (tid < 256)      cqbL[tid] = cqb[bh * 256 + tid];
  else if (tid < 320) gbL[tid - 256] = gb[h * 64 + (tid - 256)];
  __syncthreads();

  const int wid = tid >> 6, lane = tid & 63;
  const int lo = lane & 15, hi = lane >> 4;
  const int m0 = blockIdx.x * 256 + wid * 32;
  bf16* Pw = Pst[wid];

  short8 ax[2][2];
#pragma unroll
  for (int rt = 0; rt < 2; rt++)
#pragma unroll
    for (int ks = 0; ks < 2; ks++)
      ax[rt][ks] = *(const short8*)(xm +
          (size_t)(b * 16384 + m0 + rt * 16 + lo) * 512 + h * 64 +
          ks * 32 + hi * 8);

  f32x4 accS[2][4], accC[2][4];
  float l1[2][4], l2[2][4];
#pragma unroll
  for (int rt = 0; rt < 2; rt++)
#pragma unroll
    for (int dt = 0; dt < 4; dt++) {
      accS[rt][dt] = f32x4{0.f, 0.f, 0.f, 0.f};
      accC[rt][dt] = f32x4{0.f, 0.f, 0.f, 0.f};
      l1[rt][dt] = 0.f;
      l2[rt][dt] = 0.f;
    }

  attn_part<2, 64>(GkB, zTB, gbL, ax, Pw, lo, hi, accS, l1);
  attn_part<8, 256>(ckqB, cvTB, cqbL, ax, Pw, lo, hi, accC, l2);

#pragma unroll
  for (int rt = 0; rt < 2; rt++)
#pragma unroll
    for (int r = 0; r < 4; r++) {
      float a = l1[rt][r], c = l2[rt][r];
      for (int m = 1; m < 16; m <<= 1) {
        a += __shfl_xor(a, m);
        c += __shfl_xor(c, m);
      }
      l1[rt][r] = 1.f / a;
      l2[rt][r] = 1.f / c;
    }

  const int bf = *flagp;
  const float wmix = 1.f / (1.f + __expf(-ldf(smix, 0, bf)));
#pragma unroll
  for (int rt = 0; rt < 2; rt++)
#pragma unroll
    for (int r = 0; r < 4; r++) {
      int row = m0 + rt * 16 + hi * 4 + r;
      size_t off = (size_t)(b * 16384 + row) * 512 + h * 64;
#pragma unroll
      for (int dt = 0; dt < 4; dt++) {
        float vS = accS[rt][dt][r] * l1[rt][r];
        float vC = accC[rt][dt][r] * l2[rt][r];
        selfmid[off + dt * 16 + lo] = (bf16)(wmix * vS + (1.f - wmix) * vC);
      }
    }
}

// ---------------------------------------------------------------------------
extern "C" void kernel_launch(void* const* d_in, const int* in_sizes, int n_in,
                              void* d_out, int out_size, void* d_ws, size_t ws_size,
                              hipStream_t stream)
{
  const void* x    = d_in[0];
  const void* ctx  = d_in[1];
  const void* qg   = d_in[2];
  const void* Wp   = d_in[3];  const void* bp  = d_in[4];
  const void* Wk   = d_in[5];  const void* bk  = d_in[6];
  const void* Wv   = d_in[7];  const void* bv  = d_in[8];
  const void* Wcq  = d_in[9];  const void* bcq = d_in[10];
  const void* Wck  = d_in[11]; const void* bck = d_in[12];
  const void* Wcv  = d_in[13]; const void* bcv = d_in[14];
  const void* smix = d_in[15];
  const void* Wo   = d_in[16]; const void* bo  = d_in[17];

  char* ws = (char*)d_ws;
  int*   flag    = (int*)(ws);                   // 256 B reserved
  float* ck      = (float*)(ws + 256);           // 1,048,576 (dead after k_fold)
  float* cv      = (float*)(ws + 1048832);       // 1,048,576
  float* ckq     = (float*)(ws + 2097408);       // 1,048,576
  float* cqb     = (float*)(ws + 3145984);       // 16,384
  float* Gk      = (float*)(ws + 3162368);       // 131,072
  float* gb      = (float*)(ws + 3293440);       // 2,048
  float* z       = (float*)(ws + 4348160);       // 1,048,576
  bf16*  xm      = (bf16*)(ws + 5396736);        // 33,554,432 (bf16)
  bf16*  selfmid = (bf16*)(ws + 38951168);       // 33,554,432 (bf16)
  // WpT/WoT reuse the ck region (dead after k_fold)
  bf16*  WpT     = (bf16*)(ws + 256);
  bf16*  WoT     = (bf16*)(ws + 256 + 524288);
  // zpart/lpart park in the selfmid region (dead until k_attn)
  float* zpart   = (float*)(ws + 38951168);
  float* lpart   = (float*)(ws + 38951168 + 8388608);

  k_detect<<<1, 64, 0, stream>>>(x, flag);

  k_ctx<<<1024, 256, 0, stream>>>(flag, ctx, Wck, bck, Wcv, bcv, ck, cv);
  k_fold<<<1152, 256, 0, stream>>>(flag, ck, Wcq, bcq, qg, Wk, bk,
                                   ckq, cqb, Gk, gb);

  k_wtr<<<128, 256, 0, stream>>>(flag, Wp, Wo, WpT, WoT);

  // x_mid (flat (b,n,h*64+d), bf16) = x @ Wp + bp   [MFMA]
  k_gemm_mfma<<<dim3(4, 256), 256, 0, stream>>>(flag, x, 0, WpT, bp, xm, 0);

  // z partials via MFMA split-K over tokens
  k_stageB<<<dim3(32, 16), 256, 0, stream>>>(Gk, gb, xm, zpart, lpart);
  k_znorm<<<16, 256, 0, stream>>>(flag, zpart, lpart, Wv, bv, z);

  // merged MFMA self+cross attention + sigmoid mix -> selfmid
  k_attn<<<dim3(64, 16), 512, 0, stream>>>(flag, Gk, gb, z, ckq, cqb, cv, xm,
                                           smix, selfmid);

  // out = selfmid @ Wo + bo  (output dtype chosen by flag)   [MFMA]
  k_gemm_mfma<<<dim3(4, 256), 256, 0, stream>>>(flag, selfmid, 1, WoT, bo,
                                                d_out, 1);
}